// Round 8
// baseline (986.902 us; speedup 1.0000x reference)
//
#include <hip/hip_runtime.h>
#include <hip/hip_bf16.h>
#include <math.h>

// ============================================================================
// Round 7: flash6 (self: m-tile 32, S=4, defer-max, 3 blocks/CU) + gemm3 with
// glld16 dbuf staging + fused weight-prep/transpose dispatches.
// Cross flash4 and conv5 unchanged (known-good).
// ============================================================================

#define NPIX 4096
#define NB   4

typedef __attribute__((ext_vector_type(8))) short short8v;
typedef __attribute__((ext_vector_type(4))) float float4v;

__device__ __forceinline__ short f2bs(float f) {
  __hip_bfloat16 h = __float2bfloat16(f);
  short r; __builtin_memcpy(&r, &h, 2); return r;
}

__device__ __forceinline__ void glld16(const void* g, void* l) {
  __builtin_amdgcn_global_load_lds(
      (const __attribute__((address_space(1))) unsigned int*)g,
      (__attribute__((address_space(3))) unsigned int*)l, 16, 0, 0);
}

__device__ __forceinline__ void vbar() { __builtin_amdgcn_s_barrier(); }

// ---------------- fused transpose: z<4 -> x, else y.  [B][512][N] f32 -> [B][N][512] bf16
__global__ __launch_bounds__(256) void transp_kernel(
    const float* __restrict__ X, const float* __restrict__ Y,
    __hip_bfloat16* __restrict__ XT, __hip_bfloat16* __restrict__ YT)
{
  const int i0 = blockIdx.x * 64, n0 = blockIdx.y * 64;
  const int z = blockIdx.z, b = z & 3;
  const float* S = (z < 4) ? X : Y;
  __hip_bfloat16* D = (z < 4) ? XT : YT;
  const int tid = threadIdx.x;
  __shared__ float Ls[64][68];
#pragma unroll
  for (int it = 0; it < 4; ++it) {
    int ir = it * 16 + (tid >> 4);
    int nc = (tid & 15) * 4;
    float4 v = *(const float4*)(S + ((size_t)b * 512 + i0 + ir) * NPIX + n0 + nc);
    *(float4*)(&Ls[ir][nc]) = v;
  }
  __syncthreads();
#pragma unroll
  for (int ot = 0; ot < 2; ++ot) {
    int n = ot * 32 + (tid >> 3);
    int ig = tid & 7;
    short8v o;
#pragma unroll
    for (int j = 0; j < 8; ++j) o[j] = f2bs(Ls[8 * ig + j][n]);
    *(short8v*)(D + ((size_t)b * NPIX + n0 + n) * 512 + i0 + 8 * ig) = o;
  }
}

// ---------------- fused weight prep (9 segments in one dispatch)
// seg 0..6: dense [Or][Ir] -> [Op][Ip]; seg 7,8: conv [O][Ir][3][3] -> [9][O][Ip]
__global__ void wprep_all(
    const float* __restrict__ w1, const float* __restrict__ cq,
    const float* __restrict__ ck, const float* __restrict__ cv,
    const float* __restrict__ sq, const float* __restrict__ sk,
    const float* __restrict__ sv, const float* __restrict__ c1,
    const float* __restrict__ c2,
    __hip_bfloat16* __restrict__ w1o, __hip_bfloat16* __restrict__ cqo,
    __hip_bfloat16* __restrict__ cko, __hip_bfloat16* __restrict__ cvo,
    __hip_bfloat16* __restrict__ sqo, __hip_bfloat16* __restrict__ sko,
    __hip_bfloat16* __restrict__ svo, __hip_bfloat16* __restrict__ c1o,
    __hip_bfloat16* __restrict__ c2o)
{
  const int seg = blockIdx.y;
  const float* src; __hip_bfloat16* dst;
  int Or, Ir, Op, Ip, isconv = 0;
  switch (seg) {
    case 0: src = w1; dst = w1o; Or = 256; Ir = 512; Op = 256; Ip = 512; break;
    case 1: src = cq; dst = cqo; Or = 256; Ir = 256; Op = 256; Ip = 256; break;
    case 2: src = ck; dst = cko; Or = 256; Ir = 256; Op = 256; Ip = 256; break;
    case 3: src = cv; dst = cvo; Or = 256; Ir = 256; Op = 256; Ip = 256; break;
    case 4: src = sq; dst = sqo; Or = 258; Ir = 258; Op = 320; Ip = 288; break;
    case 5: src = sk; dst = sko; Or = 258; Ir = 258; Op = 320; Ip = 288; break;
    case 6: src = sv; dst = svo; Or = 258; Ir = 258; Op = 320; Ip = 288; break;
    case 7: src = c1; dst = c1o; Or = 256; Ir = 256; Op = 256; Ip = 256; isconv = 1; break;
    default: src = c2; dst = c2o; Or = 256; Ir = 258; Op = 256; Ip = 288; isconv = 1; break;
  }
  if (!isconv) {
    size_t total = (size_t)Op * Ip;
    for (size_t e = (size_t)blockIdx.x * 256 + threadIdx.x; e < total;
         e += (size_t)gridDim.x * 256) {
      int i = (int)(e % Ip), o = (int)(e / Ip);
      float v = (o < Or && i < Ir) ? src[(size_t)o * Ir + i] : 0.f;
      dst[e] = __float2bfloat16(v);
    }
  } else {
    size_t total = (size_t)9 * Op * Ip;
    for (size_t e = (size_t)blockIdx.x * 256 + threadIdx.x; e < total;
         e += (size_t)gridDim.x * 256) {
      int i = (int)(e % Ip);
      size_t r = e / Ip;
      int o = (int)(r % Op);
      int dydx = (int)(r / Op);
      float v = (i < Ir) ? src[((size_t)o * Ir + i) * 9 + dydx] : 0.f;
      dst[e] = __float2bfloat16(v);
    }
  }
}

// ---------------- MFMA 1x1 GEMM, glld16 + dbuf LDS.
// X: [B][N][Ip] bf16, Wb: [Opad][Ip] bf16.
// OMODE 0: f32+bf16 [B][N][O] (+bias); 1: bf16 [B][N][O] (+bias)
// OMODE 3: bf16 K-chunk [B][O/8][N][8]; 4: bf16 V-chunk [B][N/8][O][8]
template<int OMODE>
__global__ __launch_bounds__(256, 3) void gemm3_kernel(
    const __hip_bfloat16* __restrict__ X, const __hip_bfloat16* __restrict__ Wb,
    const float* __restrict__ Bias, float* __restrict__ Yf,
    __hip_bfloat16* __restrict__ Yb, int Ip, int O)
{
  const int n0 = blockIdx.x * 64, o0 = blockIdx.y * 64, b = blockIdx.z;
  const int tid = threadIdx.x, wv = tid >> 6, lane = tid & 63;
  const int lg = lane >> 4, lr = lane & 15;
  __shared__ __align__(1024) __hip_bfloat16 Xs[2][64 * 32];
  __shared__ __align__(1024) __hip_bfloat16 Wsh[2][64 * 32];

  const int nn = tid >> 2, ig = tid & 3;
  // pre-swizzled global source (rule #21): LDS stays linear
  const __hip_bfloat16* xsrc = X + ((size_t)b * NPIX + n0 + nn) * Ip + 8 * (ig ^ (nn & 3));
  const __hip_bfloat16* wsrc = Wb + (size_t)(o0 + nn) * Ip + 8 * (ig ^ (nn & 3));

  float4v acc[4];
#pragma unroll
  for (int f = 0; f < 4; ++f) acc[f] = (float4v){0.f, 0.f, 0.f, 0.f};

  const int nch = Ip >> 5;

#define GSTAGE(BUF, CI)                            \
  glld16(xsrc + (CI) * 32, &Xs[BUF][tid * 8]);     \
  glld16(wsrc + (CI) * 32, &Wsh[BUF][tid * 8]);

  GSTAGE(0, 0);
  int cur = 0;
  for (int ci = 0; ci < nch; ++ci) {
    asm volatile("s_waitcnt vmcnt(0)" ::: "memory");
    __syncthreads();
    if (ci + 1 < nch) {
      if (cur) { GSTAGE(0, ci + 1); } else { GSTAGE(1, ci + 1); }
    }
    const __hip_bfloat16* xb = &Xs[cur][0];
    const __hip_bfloat16* wb = &Wsh[cur][0];
    if (OMODE != 4) {
      int ar = 16 * wv + lr;
      short8v a = *(const short8v*)(xb + ar * 32 + 8 * (lg ^ (ar & 3)));
#pragma unroll
      for (int of = 0; of < 4; ++of) {
        int br = 16 * of + lr;
        short8v bbv = *(const short8v*)(wb + br * 32 + 8 * (lg ^ (br & 3)));
        acc[of] = __builtin_amdgcn_mfma_f32_16x16x32_bf16(a, bbv, acc[of], 0, 0, 0);
      }
    } else {
      int ar = 16 * wv + lr;
      short8v a = *(const short8v*)(wb + ar * 32 + 8 * (lg ^ (ar & 3)));
#pragma unroll
      for (int nf = 0; nf < 4; ++nf) {
        int br = 16 * nf + lr;
        short8v bbv = *(const short8v*)(xb + br * 32 + 8 * (lg ^ (br & 3)));
        acc[nf] = __builtin_amdgcn_mfma_f32_16x16x32_bf16(a, bbv, acc[nf], 0, 0, 0);
      }
    }
    cur ^= 1;
  }
#undef GSTAGE

  if (OMODE < 2) {
#pragma unroll
    for (int r = 0; r < 4; ++r) {
      size_t row = (size_t)b * NPIX + n0 + 16 * wv + 4 * lg + r;
#pragma unroll
      for (int of = 0; of < 4; ++of) {
        int o = o0 + 16 * of + lr;
        if (o < O) {
          float v = acc[of][r] + (Bias ? Bias[o] : 0.f);
          if (OMODE == 0) Yf[row * O + o] = v;
          Yb[row * O + o] = __float2bfloat16(v);
        }
      }
    }
  } else if (OMODE == 3) {
    __hip_bfloat16* Hb = Yb + (size_t)b * NPIX * O;
#pragma unroll
    for (int r = 0; r < 4; ++r) {
      size_t n = n0 + 16 * wv + 4 * lg + r;
#pragma unroll
      for (int of = 0; of < 4; ++of) {
        int o = o0 + 16 * of + lr;
        if (o < O)
          Hb[((size_t)(o >> 3) * NPIX + n) * 8 + (o & 7)] = __float2bfloat16(acc[of][r]);
      }
    }
  } else {  // OMODE 4
    __hip_bfloat16* Hb = Yb + (size_t)b * NPIX * O;
#pragma unroll
    for (int r = 0; r < 4; ++r) {
      int c = o0 + 16 * wv + 4 * lg + r;
      if (c < O) {
#pragma unroll
        for (int nf = 0; nf < 4; ++nf) {
          int n = n0 + 16 * nf + lr;
          Hb[((size_t)(n >> 3) * O + c) * 8 + (n & 7)] = __float2bfloat16(acc[nf][r]);
        }
      }
    }
  }
}

// ---------------- flash4 (cross, known-good): chunked LDS + glld16, m-tile 64.
template<int C, int RF, int S>
__global__ __launch_bounds__(256, 2) void flash4_kernel(
    const __hip_bfloat16* __restrict__ Q, const __hip_bfloat16* __restrict__ K,
    const __hip_bfloat16* __restrict__ V,
    __hip_bfloat16* __restrict__ Opart, float* __restrict__ ml)
{
  constexpr int N    = NPIX;
  constexpr int NC32 = C / 32;
  constexpr int NCF  = C / 16;
  constexpr int QB   = 16 * RF;
  constexpr int KBYTES = 128 * C;
  constexpr int NT   = (N / S) / 64;

  __shared__ __align__(1024) char smem[256 * C];
  __hip_bfloat16* Ks = (__hip_bfloat16*)smem;
  __hip_bfloat16* Vs = (__hip_bfloat16*)(smem + KBYTES);
  __hip_bfloat16* Ps = (__hip_bfloat16*)smem;   // alias

  const int n0 = blockIdx.x * (4 * QB);
  const int split = blockIdx.y, b = blockIdx.z;
  const int tid = threadIdx.x, w = tid >> 6, lane = tid & 63;
  const int lg = lane >> 4, lr = lane & 15;

  const __hip_bfloat16* Kb = K + (size_t)b * N * C;
  const __hip_bfloat16* Vb = V + (size_t)b * N * C;

  short8v qf[RF][NC32];
#pragma unroll
  for (int rf = 0; rf < RF; ++rf) {
    const __hip_bfloat16* qp =
        Q + ((size_t)b * N + n0 + QB * w + 16 * rf + lr) * C + 8 * lg;
#pragma unroll
    for (int ks = 0; ks < NC32; ++ks) qf[rf][ks] = *(const short8v*)(qp + 32 * ks);
  }

  float4v oacc[RF][NCF];
#pragma unroll
  for (int rf = 0; rf < RF; ++rf)
#pragma unroll
    for (int f = 0; f < NCF; ++f) oacc[rf][f] = (float4v){0.f, 0.f, 0.f, 0.f};
  float mrun[RF][4], lrun[RF][4];
#pragma unroll
  for (int rf = 0; rf < RF; ++rf)
#pragma unroll
    for (int r = 0; r < 4; ++r) { mrun[rf][r] = -INFINITY; lrun[rf][r] = 0.f; }

  const int m0base = split * (N / S);

  for (int t = 0; t < NT; ++t) {
    const int m0 = m0base + t * 64;
    __syncthreads();
    for (int u = w; u < C / 8; u += 4)
      glld16(Kb + ((size_t)u * N + m0 + lane) * 8, Ks + u * 512);
    for (int u = w; u < C / 8; u += 4) {
      int s = u * 64 + lane;
      int kv8 = s / C, c = s % C;
      glld16(Vb + ((size_t)(m0 / 8 + kv8) * C + c) * 8, Vs + u * 512);
    }
    asm volatile("s_waitcnt vmcnt(0)" ::: "memory");
    __syncthreads();

    float4v sacc[RF][4];
#pragma unroll
    for (int rf = 0; rf < RF; ++rf)
#pragma unroll
      for (int mf = 0; mf < 4; ++mf) sacc[rf][mf] = (float4v){0.f, 0.f, 0.f, 0.f};
    __builtin_amdgcn_s_setprio(1);
#pragma unroll
    for (int ks = 0; ks < NC32; ++ks)
#pragma unroll
      for (int mf = 0; mf < 4; ++mf) {
        short8v kf = *(const short8v*)(Ks + ((4 * ks + lg) * 64 + 16 * mf + lr) * 8);
#pragma unroll
        for (int rf = 0; rf < RF; ++rf)
          sacc[rf][mf] =
              __builtin_amdgcn_mfma_f32_16x16x32_bf16(qf[rf][ks], kf, sacc[rf][mf], 0, 0, 0);
      }
    __builtin_amdgcn_s_setprio(0);
    __syncthreads();

    float scal[RF][4];
#pragma unroll
    for (int rf = 0; rf < RF; ++rf)
#pragma unroll
      for (int r = 0; r < 4; ++r) {
        float pm = fmaxf(fmaxf(sacc[rf][0][r], sacc[rf][1][r]),
                         fmaxf(sacc[rf][2][r], sacc[rf][3][r]));
#pragma unroll
        for (int off = 1; off < 16; off <<= 1) pm = fmaxf(pm, __shfl_xor(pm, off));
        float mnew = fmaxf(mrun[rf][r], pm);
        float sc = __expf(mrun[rf][r] - mnew);
        mrun[rf][r] = mnew;
        float rs = 0.f;
#pragma unroll
        for (int mf = 0; mf < 4; ++mf) {
          float p = __expf(sacc[rf][mf][r] - mnew);
          rs += p;
          Ps[(size_t)(w * QB + 16 * rf + 4 * lg + r) * 72 + 16 * mf + lr] =
              __float2bfloat16(p);
        }
#pragma unroll
        for (int off = 1; off < 16; off <<= 1) rs += __shfl_xor(rs, off);
        lrun[rf][r] = lrun[rf][r] * sc + rs;
        scal[rf][r] = sc;
      }
#pragma unroll
    for (int rf = 0; rf < RF; ++rf)
#pragma unroll
      for (int f = 0; f < NCF; ++f)
#pragma unroll
        for (int r = 0; r < 4; ++r) oacc[rf][f][r] *= scal[rf][r];

    asm volatile("s_waitcnt lgkmcnt(0)" ::: "memory");

    short8v pa[RF][2];
#pragma unroll
    for (int rf = 0; rf < RF; ++rf)
#pragma unroll
      for (int h = 0; h < 2; ++h)
        pa[rf][h] = *(const short8v*)(Ps + (size_t)(w * QB + 16 * rf + lr) * 72 +
                                      32 * h + 8 * lg);
    __builtin_amdgcn_s_setprio(1);
#pragma unroll
    for (int cf = 0; cf < NCF; ++cf)
#pragma unroll
      for (int h = 0; h < 2; ++h) {
        short8v vf = *(const short8v*)(Vs + ((h * 4 + lg) * C + 16 * cf + lr) * 8);
#pragma unroll
        for (int rf = 0; rf < RF; ++rf)
          oacc[rf][cf] =
              __builtin_amdgcn_mfma_f32_16x16x32_bf16(pa[rf][h], vf, oacc[rf][cf], 0, 0, 0);
      }
    __builtin_amdgcn_s_setprio(0);
  }

  const size_t rbase = (size_t)(split * NB + b) * N;
#pragma unroll
  for (int rf = 0; rf < RF; ++rf)
#pragma unroll
    for (int r = 0; r < 4; ++r) {
      int n = n0 + QB * w + 16 * rf + 4 * lg + r;
      if (lr == 0) {
        ml[(rbase + n) * 2]     = mrun[rf][r];
        ml[(rbase + n) * 2 + 1] = lrun[rf][r];
      }
#pragma unroll
      for (int cf = 0; cf < NCF; ++cf)
        Opart[(rbase + n) * C + 16 * cf + lr] = __float2bfloat16(oacc[rf][cf][r]);
    }
}

// ---------------- flash6 (self): m-tile 32, RF=1, defer-max, 36 KB LDS.
// Q: [B][N][C].  K: [B][C/8][N][8].  V: [B][N/8][C][8].  KV-split S.
template<int C, int S>
__global__ __launch_bounds__(256, 3) void flash6_kernel(
    const __hip_bfloat16* __restrict__ Q, const __hip_bfloat16* __restrict__ K,
    const __hip_bfloat16* __restrict__ V,
    __hip_bfloat16* __restrict__ Opart, float* __restrict__ ml)
{
  constexpr int N    = NPIX;
  constexpr int NC32 = C / 32;       // 9
  constexpr int NCF  = C / 16;       // 18
  constexpr int KBYTES = (C / 8) * 32 * 8 * 2;   // 18432
  constexpr int NINST = C / 16;      // 18 glld16 per K and per V tile
  constexpr int NT   = (N / S) / 32;

  __shared__ __align__(1024) char smem[2 * KBYTES];
  __hip_bfloat16* Ks = (__hip_bfloat16*)smem;              // [C/8][32][8]
  __hip_bfloat16* Vs = (__hip_bfloat16*)(smem + KBYTES);   // [4][C][8]
  __hip_bfloat16* Ps = (__hip_bfloat16*)smem;              // alias: [64][40]

  const int n0 = blockIdx.x * 64;
  const int split = blockIdx.y, b = blockIdx.z;
  const int tid = threadIdx.x, w = tid >> 6, lane = tid & 63;
  const int lg = lane >> 4, lr = lane & 15;

  const __hip_bfloat16* Kb = K + (size_t)b * N * C;
  const __hip_bfloat16* Vb = V + (size_t)b * N * C;

  // Q fragments: rows n0 + 16w + lr
  short8v qf[NC32];
  {
    const __hip_bfloat16* qp = Q + ((size_t)b * N + n0 + 16 * w + lr) * C + 8 * lg;
#pragma unroll
    for (int ks = 0; ks < NC32; ++ks) qf[ks] = *(const short8v*)(qp + 32 * ks);
  }

  float4v oacc[NCF];
#pragma unroll
  for (int f = 0; f < NCF; ++f) oacc[f] = (float4v){0.f, 0.f, 0.f, 0.f};
  float mrun[4], lrun[4];
#pragma unroll
  for (int r = 0; r < 4; ++r) { mrun[r] = -INFINITY; lrun[r] = 0.f; }

  const int m0base = split * (N / S);

  for (int t = 0; t < NT; ++t) {
    const int m0 = m0base + t * 32;
    __syncthreads();                 // prev-tile P/V reads complete
    // stage K: instr u covers c8-chunks {2u, 2u+1}, m = lane&31
    for (int u = w; u < NINST; u += 4)
      glld16(Kb + ((size_t)(2 * u + (lane >> 5)) * N + m0 + (lane & 31)) * 8,
             Ks + u * 512);
    // stage V: slot s = (kv8, c); s = u*64 + lane
    for (int u = w; u < NINST; u += 4) {
      int s = u * 64 + lane;
      int kv8 = s / C, c = s % C;
      glld16(Vb + ((size_t)(m0 / 8 + kv8) * C + c) * 8, Vs + s * 8);
    }
    asm volatile("s_waitcnt vmcnt(0)" ::: "memory");
    __syncthreads();

    // ---- S = Q^T K (16 rows x 32 m)
    float4v sacc[2];
#pragma unroll
    for (int mf = 0; mf < 2; ++mf) sacc[mf] = (float4v){0.f, 0.f, 0.f, 0.f};
    __builtin_amdgcn_s_setprio(1);
#pragma unroll
    for (int ks = 0; ks < NC32; ++ks)
#pragma unroll
      for (int mf = 0; mf < 2; ++mf) {
        short8v kf = *(const short8v*)(Ks + ((4 * ks + lg) * 32 + 16 * mf + lr) * 8);
        sacc[mf] = __builtin_amdgcn_mfma_f32_16x16x32_bf16(qf[ks], kf, sacc[mf], 0, 0, 0);
      }
    __builtin_amdgcn_s_setprio(0);
    __syncthreads();                 // K reads done before P writes (alias)

    // ---- online softmax with defer-max (THR=8)
    float pm[4];
#pragma unroll
    for (int r = 0; r < 4; ++r) {
      float p = fmaxf(sacc[0][r], sacc[1][r]);
#pragma unroll
      for (int off = 1; off < 16; off <<= 1) p = fmaxf(p, __shfl_xor(p, off));
      pm[r] = p;
    }
    int myok = 1;
#pragma unroll
    for (int r = 0; r < 4; ++r) myok &= (pm[r] <= mrun[r] + 8.f) ? 1 : 0;
    if (__all(myok)) {
#pragma unroll
      for (int r = 0; r < 4; ++r) {
        float rs = 0.f;
#pragma unroll
        for (int mf = 0; mf < 2; ++mf) {
          float p = __expf(sacc[mf][r] - mrun[r]);
          rs += p;
          Ps[(16 * w + 4 * lg + r) * 40 + 16 * mf + lr] = __float2bfloat16(p);
        }
#pragma unroll
        for (int off = 1; off < 16; off <<= 1) rs += __shfl_xor(rs, off);
        lrun[r] += rs;
      }
    } else {
      float scal[4];
#pragma unroll
      for (int r = 0; r < 4; ++r) {
        float mnew = fmaxf(mrun[r], pm[r]);
        float sc = __expf(mrun[r] - mnew);
        mrun[r] = mnew;
        float rs = 0.f;
#pragma unroll
        for (int mf = 0; mf < 2; ++mf) {
          float p = __expf(sacc[mf][r] - mnew);
          rs += p;
          Ps[(16 * w + 4 * lg + r) * 40 + 16 * mf + lr] = __float2bfloat16(p);
        }
#pragma unroll
        for (int off = 1; off < 16; off <<= 1) rs += __shfl_xor(rs, off);
        lrun[r] = lrun[r] * sc + rs;
        scal[r] = sc;
      }
#pragma unroll
      for (int f = 0; f < NCF; ++f)
#pragma unroll
        for (int r = 0; r < 4; ++r) oacc[f][r] *= scal[r];
    }

    asm volatile("s_waitcnt lgkmcnt(0)" ::: "memory");  // wave-private P RAW

    // ---- O += P V^T (k = 32, one MFMA per cf)
    short8v pa = *(const short8v*)(Ps + (16 * w + lr) * 40 + 8 * lg);
    __builtin_amdgcn_s_setprio(1);
#pragma unroll
    for (int cf = 0; cf < NCF; ++cf) {
      short8v vf = *(const short8v*)(Vs + (lg * C + 16 * cf + lr) * 8);
      oacc[cf] = __builtin_amdgcn_mfma_f32_16x16x32_bf16(pa, vf, oacc[cf], 0, 0, 0);
    }
    __builtin_amdgcn_s_setprio(0);
  }

  // ---- epilogue: unnormalized partials, channel-last
  const size_t rbase = (size_t)(split * NB + b) * N;
#pragma unroll
  for (int r = 0; r < 4; ++r) {
    int n = n0 + 16 * w + 4 * lg + r;
    if (lr == 0) {
      ml[(rbase + n) * 2]     = mrun[r];
      ml[(rbase + n) * 2 + 1] = lrun[r];
    }
#pragma unroll
    for (int cf = 0; cf < NCF; ++cf)
      Opart[(rbase + n) * C + 16 * cf + lr] = __float2bfloat16(oacc[cf][r]);
  }
}

// ---------------- merge S splits + gamma + residual -> t bf16 [B][N][C]
template<int C, int S>
__global__ __launch_bounds__(256) void merge4_kernel(
    const __hip_bfloat16* __restrict__ Op, const float* __restrict__ ml,
    const float* __restrict__ R, const float* __restrict__ gamma_p,
    __hip_bfloat16* __restrict__ T)
{
  const size_t row = blockIdx.x;
  float m = -INFINITY;
#pragma unroll
  for (int s = 0; s < S; ++s)
    m = fmaxf(m, ml[((size_t)s * NB * NPIX + row) * 2]);
  float e[S]; float L = 0.f;
#pragma unroll
  for (int s = 0; s < S; ++s) {
    e[s] = __expf(ml[((size_t)s * NB * NPIX + row) * 2] - m);
    L += ml[((size_t)s * NB * NPIX + row) * 2 + 1] * e[s];
  }
  float rinv = gamma_p[0] / L;
  for (int c = threadIdx.x; c < C; c += 256) {
    float o = 0.f;
#pragma unroll
    for (int s = 0; s < S; ++s)
      o += __bfloat162float(Op[((size_t)s * NB * NPIX + row) * C + c]) * e[s];
    T[row * C + c] = __float2bfloat16(o * rinv + R[row * C + c]);
  }
}

// ---------------- conv5 (unchanged, known-good)
template<int IC>
__global__ __launch_bounds__(256, 1) void conv5_kernel(
    const __hip_bfloat16* __restrict__ X, const __hip_bfloat16* __restrict__ W2,
    float* __restrict__ Y)
{
  constexpr int NCH = IC / 32;
  constexpr int XP = 66 * 32;
  const int h0 = blockIdx.x * 4, o0 = blockIdx.y * 64, b = blockIdx.z;
  const int tid = threadIdx.x, wv = tid >> 6, lane = tid & 63;
  const int lg = lane >> 4, lr = lane & 15;

  __shared__ __align__(1024) __hip_bfloat16 Xs[2][6 * XP];
  __shared__ __align__(1024) __hip_bfloat16 Wsh[2][9 * 2048];

  const __hip_bfloat16 zz = __float2bfloat16(0.f);
  for (int e = tid; e < 384; e += 256) {
    int p = e / 64, side = (e >> 5) & 1, ch = e & 31;
    int sl = side ? 65 : 0;
    Xs[0][p * XP + sl * 32 + ch] = zz;
    Xs[1][p * XP + sl * 32 + ch] = zz;
  }
#pragma unroll
  for (int p = 0; p < 6; ++p) {
    int hs = h0 - 1 + p;
    if (hs < 0 || hs > 63) {
      for (int e = tid; e < XP; e += 256) {
        Xs[0][p * XP + e] = zz;
        Xs[1][p * XP + e] = zz;
      }
    }
  }
  __syncthreads();

  float4v acc[4][4];
#pragma unroll
  for (int pf = 0; pf < 4; ++pf)
#pragma unroll
    for (int of = 0; of < 4; ++of) acc[pf][of] = (float4v){0.f, 0.f, 0.f, 0.f};

#define CSTAGE(BUF, CI)                                                        \
  _Pragma("unroll")                                                            \
  for (int k = 0; k < 6; ++k) {                                                \
    int j = wv + k * 4;                                                        \
    int p = j >> 2, seg = j & 3;                                               \
    int hs = h0 - 1 + p;                                                       \
    if (hs >= 0 && hs < 64) {                                                  \
      int px = seg * 16 + (lane >> 2), ig = lane & 3;                          \
      int sl = px + 1;                                                         \
      glld16(X + ((size_t)(b * NPIX + hs * 64 + px)) * IC + (CI) * 32 +        \
                 8 * (ig ^ (sl & 3)),                                          \
             &Xs[BUF][p * XP + (1 + seg * 16) * 32]);                          \
    }                                                                          \
  }                                                                            \
  _Pragma("unroll")                                                            \
  for (int k = 0; k < 9; ++k) {                                                \
    int j = wv + k * 4;                                                        \
    int dydx = j >> 2, seg = j & 3;                                            \
    int oo = seg * 16 + (lane >> 2), ig = lane & 3;                            \
    glld16(W2 + ((size_t)(dydx * 256 + o0 + oo)) * IC + (CI) * 32 +            \
               8 * (ig ^ (oo & 3)),                                            \
           &Wsh[BUF][dydx * 2048 + seg * 512]);                                \
  }

  CSTAGE(0, 0);
  int cur = 0;
  for (int ci = 0; ci < NCH; ++ci) {
    asm volatile("s_waitcnt vmcnt(0) lgkmcnt(0)" ::: "memory");
    vbar();
    __builtin_amdgcn_sched_barrier(0);
    const int cn = (ci + 1 == NCH) ? 0 : ci + 1;
    if (cur) { CSTAGE(0, cn); } else { CSTAGE(1, cn); }
    const __hip_bfloat16* xb = &Xs[cur][0];
    const __hip_bfloat16* wb = &Wsh[cur][0];
    __builtin_amdgcn_s_setprio(1);
#pragma unroll
    for (int dy = 0; dy < 3; ++dy) {
      const __hip_bfloat16* xpl = xb + (wv + dy) * XP;
#pragma unroll
      for (int dx = 0; dx < 3; ++dx) {
        short8v a[4];
#pragma unroll
        for (int pf = 0; pf < 4; ++pf) {
          int sl = pf * 16 + lr + dx;
          a[pf] = *(const short8v*)(xpl + sl * 32 + 8 * (lg ^ (sl & 3)));
        }
#pragma unroll
        for (int of = 0; of < 4; ++of) {
          int br = 16 * of + lr;
          short8v bbv = *(const short8v*)(wb + (dy * 3 + dx) * 2048 + br * 32 +
                                          8 * (lg ^ (br & 3)));
#pragma unroll
          for (int pf = 0; pf < 4; ++pf)
            acc[pf][of] = __builtin_amdgcn_mfma_f32_16x16x32_bf16(a[pf], bbv,
                                                                  acc[pf][of], 0, 0, 0);
        }
      }
    }
    __builtin_amdgcn_s_setprio(0);
    cur ^= 1;
  }
#undef CSTAGE

#pragma unroll
  for (int pf = 0; pf < 4; ++pf)
#pragma unroll
    for (int r = 0; r < 4; ++r) {
      size_t row = (size_t)b * NPIX + (h0 + wv) * 64 + 16 * pf + 4 * lg + r;
#pragma unroll
      for (int of = 0; of < 4; ++of)
        Y[row * 256 + o0 + 16 * of + lr] = acc[pf][of][r];
    }
}

// ---------------- BN stats, two-stage. X: [16384][256] f32.
__global__ __launch_bounds__(256) void stats1_kernel(
    const float* __restrict__ X, float* __restrict__ Part)
{
  const int o0 = (blockIdx.x & 3) * 64;
  const int rc = blockIdx.x >> 2;
  const int tid = threadIdx.x;
  const int o = o0 + (tid & 63), rq = tid >> 6;
  float s = 0.f, sq = 0.f;
  for (int rr = rq; rr < 256; rr += 4) {
    float v = X[(size_t)(rc * 256 + rr) * 256 + o];
    s += v; sq += v * v;
  }
  __shared__ float rs[256], rq2[256];
  rs[tid] = s; rq2[tid] = sq;
  __syncthreads();
  if (tid < 64) {
    s  = rs[tid] + rs[tid + 64] + rs[tid + 128] + rs[tid + 192];
    sq = rq2[tid] + rq2[tid + 64] + rq2[tid + 128] + rq2[tid + 192];
    Part[(o0 + tid) * 128 + rc * 2]     = s;
    Part[(o0 + tid) * 128 + rc * 2 + 1] = sq;
  }
}

__global__ __launch_bounds__(256) void stats2_kernel(
    const float* __restrict__ Part, float* __restrict__ Mean, float* __restrict__ Rstd)
{
  const int o = threadIdx.x;
  float s = 0.f, sq = 0.f;
  for (int rc = 0; rc < 64; ++rc) {
    s += Part[o * 128 + rc * 2];
    sq += Part[o * 128 + rc * 2 + 1];
  }
  float mean = s / 16384.f;
  float var = sq / 16384.f - mean * mean;
  Mean[o] = mean;
  Rstd[o] = 1.f / sqrtf(var + 1e-5f);
}

// ---------------- BN apply #1 + ReLU + cat flow -> cat f32/bf16 [16384][288]
__global__ __launch_bounds__(320) void bnapply1_kernel(
    const float* __restrict__ X, const float* __restrict__ Flow,
    const float* __restrict__ Mean, const float* __restrict__ Rstd,
    const float* __restrict__ G, const float* __restrict__ Bt,
    float* __restrict__ CatF, __hip_bfloat16* __restrict__ CatB)
{
  const size_t row = blockIdx.x;
  const int t = threadIdx.x;
  if (t >= 288) return;
  float val;
  if (t < 256) {
    float v = X[row * 256 + t];
    val = fmaxf((v - Mean[t]) * Rstd[t] * G[t] + Bt[t], 0.f);
  } else if (t < 258) {
    int b = (int)(row >> 12), n = (int)(row & 4095);
    val = Flow[((size_t)(b * 2 + (t - 256)) << 12) + n];
  } else val = 0.f;
  CatF[row * 288 + t] = val;
  CatB[row * 288 + t] = __float2bfloat16(val);
}

// ---------------- BN apply #2 + ReLU, in place on [16384][256] f32
__global__ __launch_bounds__(256) void bnapply2_kernel(
    float* X, const float* __restrict__ Mean, const float* __restrict__ Rstd,
    const float* __restrict__ G, const float* __restrict__ Bt)
{
  const size_t idx = (size_t)blockIdx.x * 256 + threadIdx.x;
  const int t = threadIdx.x;
  float v = X[idx];
  X[idx] = fmaxf((v - Mean[t]) * Rstd[t] * G[t] + Bt[t], 0.f);
}

// ---------------- pred: out[row] = dot(X[row][0:256], W) + bias
__global__ __launch_bounds__(256) void pred3_kernel(
    const float* __restrict__ X, const float* __restrict__ Wp,
    const float* __restrict__ Bp, float* __restrict__ Out)
{
  const int wv = threadIdx.x >> 6, lane = threadIdx.x & 63;
  const size_t row = (size_t)blockIdx.x * 4 + wv;
  const float* xr = X + row * 256;
  float acc = 0.f;
#pragma unroll
  for (int cc = 0; cc < 4; ++cc) acc = fmaf(xr[cc * 64 + lane], Wp[cc * 64 + lane], acc);
#pragma unroll
  for (int off = 1; off < 64; off <<= 1) acc += __shfl_xor(acc, off);
  if (lane == 0) Out[row] = acc + Bp[0];
}

// ============================================================================
extern "C" void kernel_launch(void* const* d_in, const int* in_sizes, int n_in,
                              void* d_out, int out_size, void* d_ws, size_t ws_size,
                              hipStream_t stream)
{
  (void)in_sizes; (void)n_in; (void)out_size; (void)ws_size;
  const float* x      = (const float*)d_in[0];
  const float* y      = (const float*)d_in[1];
  const float* flow   = (const float*)d_in[2];
  const float* w1x1   = (const float*)d_in[3];
  const float* b1x1   = (const float*)d_in[4];
  const float* ca_wq  = (const float*)d_in[5];
  const float* ca_wk  = (const float*)d_in[6];
  const float* ca_wv  = (const float*)d_in[7];
  const float* ca_g   = (const float*)d_in[8];
  const float* cbr1_w = (const float*)d_in[9];
  const float* bn1_g  = (const float*)d_in[10];
  const float* bn1_b  = (const float*)d_in[11];
  const float* sa_wq  = (const float*)d_in[12];
  const float* sa_wk  = (const float*)d_in[13];
  const float* sa_wv  = (const float*)d_in[14];
  const float* sa_g   = (const float*)d_in[15];
  const float* cbr2_w = (const float*)d_in[16];
  const float* bn2_g  = (const float*)d_in[17];
  const float* bn2_b  = (const float*)d_in[18];
  const float* pred_w = (const float*)d_in[19];
  const float* pred_b = (const float*)d_in[20];
  float* out = (float*)d_out;

  // ---- workspace layout (float units)
  const size_t FSZ = (size_t)NB * NPIX * 288;       // 4,718,592 floats
  const size_t SSZ = FSZ / 2;                       // bf16 slot
  float* ws = (float*)d_ws;
  float* F0 = ws;                 // xT -> cross Opart -> conv1 out -> self Opart -> conv2/bn2
  float* F1 = ws + FSZ;           // yT -> Opart tails
  float* F2 = ws + 2 * FSZ;       // xb f32 (cross residual) -> cat f32 (self residual)
  float* Sb = ws + 3 * FSZ;
  __hip_bfloat16* S0 = (__hip_bfloat16*)(Sb);            // xb_bf -> t -> q2
  __hip_bfloat16* S1 = (__hip_bfloat16*)(Sb + SSZ);      // yb_bf -> k2
  __hip_bfloat16* S2 = (__hip_bfloat16*)(Sb + 2 * SSZ);  // q -> v2
  __hip_bfloat16* S3 = (__hip_bfloat16*)(Sb + 3 * SSZ);  // k -> catT
  __hip_bfloat16* S4 = (__hip_bfloat16*)(Sb + 4 * SSZ);  // v -> t2
  float* Wr = Sb + 5 * SSZ;
  __hip_bfloat16* w1bf  = (__hip_bfloat16*)Wr;                       // 256x512
  __hip_bfloat16* caqb  = w1bf + (size_t)256 * 512;                  // 256x256
  __hip_bfloat16* cakb  = caqb + (size_t)256 * 256;
  __hip_bfloat16* cavb  = cakb + (size_t)256 * 256;
  __hip_bfloat16* saqb  = cavb + (size_t)256 * 256;                  // 320x288
  __hip_bfloat16* sakb  = saqb + (size_t)320 * 288;
  __hip_bfloat16* savb  = sakb + (size_t)320 * 288;
  __hip_bfloat16* w2abf = savb + (size_t)320 * 288;                  // 9x256x256
  __hip_bfloat16* w2bbf = w2abf + (size_t)9 * 256 * 256;             // 9x256x288
  float* Part = (float*)(w2bbf + (size_t)9 * 256 * 288);             // 32768
  float* Mean = Part + 32768;                                        // 256
  float* Rstd = Mean + 256;                                          // 256
  float* Mlb  = Rstd + 256;                                          // 131072

  __hip_bfloat16* xT = (__hip_bfloat16*)F0;
  __hip_bfloat16* yT = (__hip_bfloat16*)F1;
  __hip_bfloat16* Op = (__hip_bfloat16*)F0;   // flash partials (spans F0+F1 for S=4)

  dim3 blk(256);

  // ---- fused weight prep (1 dispatch)
  wprep_all<<<dim3(48, 9), blk, 0, stream>>>(
      w1x1, ca_wq, ca_wk, ca_wv, sa_wq, sa_wk, sa_wv, cbr1_w, cbr2_w,
      w1bf, caqb, cakb, cavb, saqb, sakb, savb, w2abf, w2bbf);

  // ---- fused transpose x+y (1 dispatch)
  transp_kernel<<<dim3(8, 64, 8), blk, 0, stream>>>(x, y, xT, yT);

  // ---- xb (f32 + bf16), yb (bf16)
  gemm3_kernel<0><<<dim3(64, 4, 4), blk, 0, stream>>>(xT, w1bf, b1x1, F2, S0, 512, 256);
  gemm3_kernel<1><<<dim3(64, 4, 4), blk, 0, stream>>>(yT, w1bf, b1x1, nullptr, S1, 512, 256);

  // ---- cross q [n][C], k chunk, v chunk
  gemm3_kernel<1><<<dim3(64, 4, 4), blk, 0, stream>>>(S0, caqb, nullptr, nullptr, S2, 256, 256);
  gemm3_kernel<3><<<dim3(64, 4, 4), blk, 0, stream>>>(S1, cakb, nullptr, nullptr, S3, 256, 256);
  gemm3_kernel<4><<<dim3(64, 4, 4), blk, 0, stream>>>(S1, cavb, nullptr, nullptr, S4, 256, 256);

  // ---- cross flash (QB=32, split 4) + merge: t = gamma*attn + xb -> S0
  flash4_kernel<256, 2, 4><<<dim3(32, 4, 4), blk, 0, stream>>>(S2, S3, S4, Op, Mlb);
  merge4_kernel<256, 4><<<dim3(16384), blk, 0, stream>>>(Op, Mlb, F2, ca_g, S0);

  // ---- conv1 + BN + ReLU + cat (cat f32 -> F2; xb dead)
  conv5_kernel<256><<<dim3(16, 4, 4), blk, 0, stream>>>(S0, w2abf, F0);
  stats1_kernel<<<dim3(256), blk, 0, stream>>>(F0, Part);
  stats2_kernel<<<dim3(1), blk, 0, stream>>>(Part, Mean, Rstd);
  bnapply1_kernel<<<dim3(16384), dim3(320), 0, stream>>>(F0, flow, Mean, Rstd,
                                                         bn1_g, bn1_b, F2, S3);

  // ---- self q2 [n][288], k2 chunk, v2 chunk
  gemm3_kernel<1><<<dim3(64, 5, 4), blk, 0, stream>>>(S3, saqb, nullptr, nullptr, S0, 288, 288);
  gemm3_kernel<3><<<dim3(64, 5, 4), blk, 0, stream>>>(S3, sakb, nullptr, nullptr, S1, 288, 288);
  gemm3_kernel<4><<<dim3(64, 5, 4), blk, 0, stream>>>(S3, savb, nullptr, nullptr, S2, 288, 288);

  // ---- self flash (m-tile 32, split 4) + merge: t2 -> S4 (R = cat f32 in F2)
  flash6_kernel<288, 4><<<dim3(64, 4, 4), blk, 0, stream>>>(S0, S1, S2, Op, Mlb);
  merge4_kernel<288, 4><<<dim3(16384), blk, 0, stream>>>(Op, Mlb, F2, sa_g, S4);

  // ---- conv2 + BN + ReLU (in place), pred
  conv5_kernel<288><<<dim3(16, 4, 4), blk, 0, stream>>>(S4, w2bbf, F0);
  stats1_kernel<<<dim3(256), blk, 0, stream>>>(F0, Part);
  stats2_kernel<<<dim3(1), blk, 0, stream>>>(Part, Mean, Rstd);
  bnapply2_kernel<<<dim3(16384), blk, 0, stream>>>(F0, Mean, Rstd, bn2_g, bn2_b);

  pred3_kernel<<<dim3(4096), blk, 0, stream>>>(F0, pred_w, pred_b, out);
}

// Round 9
// 786.389 us; speedup vs baseline: 1.2550x; 1.2550x over previous
//
#include <hip/hip_runtime.h>
#include <hip/hip_bf16.h>
#include <math.h>

// ============================================================================
// Round 8: flash7 for self-attn = C-split across wave pairs + RF=2 q-rows +
// shared P (one extra barrier), defer-max, launch_bounds(256,2) [no spill].
// Everything else = round-7 proven parts (gemm3-dbuf, fused wprep/transp,
// cross flash4, conv5).
// ============================================================================

#define NPIX 4096
#define NB   4

typedef __attribute__((ext_vector_type(8))) short short8v;
typedef __attribute__((ext_vector_type(4))) float float4v;

__device__ __forceinline__ short f2bs(float f) {
  __hip_bfloat16 h = __float2bfloat16(f);
  short r; __builtin_memcpy(&r, &h, 2); return r;
}

__device__ __forceinline__ void glld16(const void* g, void* l) {
  __builtin_amdgcn_global_load_lds(
      (const __attribute__((address_space(1))) unsigned int*)g,
      (__attribute__((address_space(3))) unsigned int*)l, 16, 0, 0);
}

__device__ __forceinline__ void vbar() { __builtin_amdgcn_s_barrier(); }

// ---------------- fused transpose: z<4 -> x, else y.  [B][512][N] f32 -> [B][N][512] bf16
__global__ __launch_bounds__(256) void transp_kernel(
    const float* __restrict__ X, const float* __restrict__ Y,
    __hip_bfloat16* __restrict__ XT, __hip_bfloat16* __restrict__ YT)
{
  const int i0 = blockIdx.x * 64, n0 = blockIdx.y * 64;
  const int z = blockIdx.z, b = z & 3;
  const float* S = (z < 4) ? X : Y;
  __hip_bfloat16* D = (z < 4) ? XT : YT;
  const int tid = threadIdx.x;
  __shared__ float Ls[64][68];
#pragma unroll
  for (int it = 0; it < 4; ++it) {
    int ir = it * 16 + (tid >> 4);
    int nc = (tid & 15) * 4;
    float4 v = *(const float4*)(S + ((size_t)b * 512 + i0 + ir) * NPIX + n0 + nc);
    *(float4*)(&Ls[ir][nc]) = v;
  }
  __syncthreads();
#pragma unroll
  for (int ot = 0; ot < 2; ++ot) {
    int n = ot * 32 + (tid >> 3);
    int ig = tid & 7;
    short8v o;
#pragma unroll
    for (int j = 0; j < 8; ++j) o[j] = f2bs(Ls[8 * ig + j][n]);
    *(short8v*)(D + ((size_t)b * NPIX + n0 + n) * 512 + i0 + 8 * ig) = o;
  }
}

// ---------------- fused weight prep (9 segments in one dispatch)
__global__ void wprep_all(
    const float* __restrict__ w1, const float* __restrict__ cq,
    const float* __restrict__ ck, const float* __restrict__ cv,
    const float* __restrict__ sq, const float* __restrict__ sk,
    const float* __restrict__ sv, const float* __restrict__ c1,
    const float* __restrict__ c2,
    __hip_bfloat16* __restrict__ w1o, __hip_bfloat16* __restrict__ cqo,
    __hip_bfloat16* __restrict__ cko, __hip_bfloat16* __restrict__ cvo,
    __hip_bfloat16* __restrict__ sqo, __hip_bfloat16* __restrict__ sko,
    __hip_bfloat16* __restrict__ svo, __hip_bfloat16* __restrict__ c1o,
    __hip_bfloat16* __restrict__ c2o)
{
  const int seg = blockIdx.y;
  const float* src; __hip_bfloat16* dst;
  int Or, Ir, Op, Ip, isconv = 0;
  switch (seg) {
    case 0: src = w1; dst = w1o; Or = 256; Ir = 512; Op = 256; Ip = 512; break;
    case 1: src = cq; dst = cqo; Or = 256; Ir = 256; Op = 256; Ip = 256; break;
    case 2: src = ck; dst = cko; Or = 256; Ir = 256; Op = 256; Ip = 256; break;
    case 3: src = cv; dst = cvo; Or = 256; Ir = 256; Op = 256; Ip = 256; break;
    case 4: src = sq; dst = sqo; Or = 258; Ir = 258; Op = 320; Ip = 288; break;
    case 5: src = sk; dst = sko; Or = 258; Ir = 258; Op = 320; Ip = 288; break;
    case 6: src = sv; dst = svo; Or = 258; Ir = 258; Op = 320; Ip = 288; break;
    case 7: src = c1; dst = c1o; Or = 256; Ir = 256; Op = 256; Ip = 256; isconv = 1; break;
    default: src = c2; dst = c2o; Or = 256; Ir = 258; Op = 256; Ip = 288; isconv = 1; break;
  }
  if (!isconv) {
    size_t total = (size_t)Op * Ip;
    for (size_t e = (size_t)blockIdx.x * 256 + threadIdx.x; e < total;
         e += (size_t)gridDim.x * 256) {
      int i = (int)(e % Ip), o = (int)(e / Ip);
      float v = (o < Or && i < Ir) ? src[(size_t)o * Ir + i] : 0.f;
      dst[e] = __float2bfloat16(v);
    }
  } else {
    size_t total = (size_t)9 * Op * Ip;
    for (size_t e = (size_t)blockIdx.x * 256 + threadIdx.x; e < total;
         e += (size_t)gridDim.x * 256) {
      int i = (int)(e % Ip);
      size_t r = e / Ip;
      int o = (int)(r % Op);
      int dydx = (int)(r / Op);
      float v = (i < Ir) ? src[((size_t)o * Ir + i) * 9 + dydx] : 0.f;
      dst[e] = __float2bfloat16(v);
    }
  }
}

// ---------------- MFMA 1x1 GEMM, glld16 + dbuf LDS (round-7 proven).
template<int OMODE>
__global__ __launch_bounds__(256, 3) void gemm3_kernel(
    const __hip_bfloat16* __restrict__ X, const __hip_bfloat16* __restrict__ Wb,
    const float* __restrict__ Bias, float* __restrict__ Yf,
    __hip_bfloat16* __restrict__ Yb, int Ip, int O)
{
  const int n0 = blockIdx.x * 64, o0 = blockIdx.y * 64, b = blockIdx.z;
  const int tid = threadIdx.x, wv = tid >> 6, lane = tid & 63;
  const int lg = lane >> 4, lr = lane & 15;
  __shared__ __align__(1024) __hip_bfloat16 Xs[2][64 * 32];
  __shared__ __align__(1024) __hip_bfloat16 Wsh[2][64 * 32];

  const int nn = tid >> 2, ig = tid & 3;
  const __hip_bfloat16* xsrc = X + ((size_t)b * NPIX + n0 + nn) * Ip + 8 * (ig ^ (nn & 3));
  const __hip_bfloat16* wsrc = Wb + (size_t)(o0 + nn) * Ip + 8 * (ig ^ (nn & 3));

  float4v acc[4];
#pragma unroll
  for (int f = 0; f < 4; ++f) acc[f] = (float4v){0.f, 0.f, 0.f, 0.f};

  const int nch = Ip >> 5;

#define GSTAGE(BUF, CI)                            \
  glld16(xsrc + (CI) * 32, &Xs[BUF][tid * 8]);     \
  glld16(wsrc + (CI) * 32, &Wsh[BUF][tid * 8]);

  GSTAGE(0, 0);
  int cur = 0;
  for (int ci = 0; ci < nch; ++ci) {
    asm volatile("s_waitcnt vmcnt(0)" ::: "memory");
    __syncthreads();
    if (ci + 1 < nch) {
      if (cur) { GSTAGE(0, ci + 1); } else { GSTAGE(1, ci + 1); }
    }
    const __hip_bfloat16* xb = &Xs[cur][0];
    const __hip_bfloat16* wb = &Wsh[cur][0];
    if (OMODE != 4) {
      int ar = 16 * wv + lr;
      short8v a = *(const short8v*)(xb + ar * 32 + 8 * (lg ^ (ar & 3)));
#pragma unroll
      for (int of = 0; of < 4; ++of) {
        int br = 16 * of + lr;
        short8v bbv = *(const short8v*)(wb + br * 32 + 8 * (lg ^ (br & 3)));
        acc[of] = __builtin_amdgcn_mfma_f32_16x16x32_bf16(a, bbv, acc[of], 0, 0, 0);
      }
    } else {
      int ar = 16 * wv + lr;
      short8v a = *(const short8v*)(wb + ar * 32 + 8 * (lg ^ (ar & 3)));
#pragma unroll
      for (int nf = 0; nf < 4; ++nf) {
        int br = 16 * nf + lr;
        short8v bbv = *(const short8v*)(xb + br * 32 + 8 * (lg ^ (br & 3)));
        acc[nf] = __builtin_amdgcn_mfma_f32_16x16x32_bf16(a, bbv, acc[nf], 0, 0, 0);
      }
    }
    cur ^= 1;
  }
#undef GSTAGE

  if (OMODE < 2) {
#pragma unroll
    for (int r = 0; r < 4; ++r) {
      size_t row = (size_t)b * NPIX + n0 + 16 * wv + 4 * lg + r;
#pragma unroll
      for (int of = 0; of < 4; ++of) {
        int o = o0 + 16 * of + lr;
        if (o < O) {
          float v = acc[of][r] + (Bias ? Bias[o] : 0.f);
          if (OMODE == 0) Yf[row * O + o] = v;
          Yb[row * O + o] = __float2bfloat16(v);
        }
      }
    }
  } else if (OMODE == 3) {
    __hip_bfloat16* Hb = Yb + (size_t)b * NPIX * O;
#pragma unroll
    for (int r = 0; r < 4; ++r) {
      size_t n = n0 + 16 * wv + 4 * lg + r;
#pragma unroll
      for (int of = 0; of < 4; ++of) {
        int o = o0 + 16 * of + lr;
        if (o < O)
          Hb[((size_t)(o >> 3) * NPIX + n) * 8 + (o & 7)] = __float2bfloat16(acc[of][r]);
      }
    }
  } else {  // OMODE 4
    __hip_bfloat16* Hb = Yb + (size_t)b * NPIX * O;
#pragma unroll
    for (int r = 0; r < 4; ++r) {
      int c = o0 + 16 * wv + 4 * lg + r;
      if (c < O) {
#pragma unroll
        for (int nf = 0; nf < 4; ++nf) {
          int n = n0 + 16 * nf + lr;
          Hb[((size_t)(n >> 3) * O + c) * 8 + (n & 7)] = __float2bfloat16(acc[nf][r]);
        }
      }
    }
  }
}

// ---------------- flash4 (cross, known-good): chunked LDS + glld16, m-tile 64.
template<int C, int RF, int S>
__global__ __launch_bounds__(256, 2) void flash4_kernel(
    const __hip_bfloat16* __restrict__ Q, const __hip_bfloat16* __restrict__ K,
    const __hip_bfloat16* __restrict__ V,
    __hip_bfloat16* __restrict__ Opart, float* __restrict__ ml)
{
  constexpr int N    = NPIX;
  constexpr int NC32 = C / 32;
  constexpr int NCF  = C / 16;
  constexpr int QB   = 16 * RF;
  constexpr int KBYTES = 128 * C;
  constexpr int NT   = (N / S) / 64;

  __shared__ __align__(1024) char smem[256 * C];
  __hip_bfloat16* Ks = (__hip_bfloat16*)smem;
  __hip_bfloat16* Vs = (__hip_bfloat16*)(smem + KBYTES);
  __hip_bfloat16* Ps = (__hip_bfloat16*)smem;   // alias

  const int n0 = blockIdx.x * (4 * QB);
  const int split = blockIdx.y, b = blockIdx.z;
  const int tid = threadIdx.x, w = tid >> 6, lane = tid & 63;
  const int lg = lane >> 4, lr = lane & 15;

  const __hip_bfloat16* Kb = K + (size_t)b * N * C;
  const __hip_bfloat16* Vb = V + (size_t)b * N * C;

  short8v qf[RF][NC32];
#pragma unroll
  for (int rf = 0; rf < RF; ++rf) {
    const __hip_bfloat16* qp =
        Q + ((size_t)b * N + n0 + QB * w + 16 * rf + lr) * C + 8 * lg;
#pragma unroll
    for (int ks = 0; ks < NC32; ++ks) qf[rf][ks] = *(const short8v*)(qp + 32 * ks);
  }

  float4v oacc[RF][NCF];
#pragma unroll
  for (int rf = 0; rf < RF; ++rf)
#pragma unroll
    for (int f = 0; f < NCF; ++f) oacc[rf][f] = (float4v){0.f, 0.f, 0.f, 0.f};
  float mrun[RF][4], lrun[RF][4];
#pragma unroll
  for (int rf = 0; rf < RF; ++rf)
#pragma unroll
    for (int r = 0; r < 4; ++r) { mrun[rf][r] = -INFINITY; lrun[rf][r] = 0.f; }

  const int m0base = split * (N / S);

  for (int t = 0; t < NT; ++t) {
    const int m0 = m0base + t * 64;
    __syncthreads();
    for (int u = w; u < C / 8; u += 4)
      glld16(Kb + ((size_t)u * N + m0 + lane) * 8, Ks + u * 512);
    for (int u = w; u < C / 8; u += 4) {
      int s = u * 64 + lane;
      int kv8 = s / C, c = s % C;
      glld16(Vb + ((size_t)(m0 / 8 + kv8) * C + c) * 8, Vs + u * 512);
    }
    asm volatile("s_waitcnt vmcnt(0)" ::: "memory");
    __syncthreads();

    float4v sacc[RF][4];
#pragma unroll
    for (int rf = 0; rf < RF; ++rf)
#pragma unroll
      for (int mf = 0; mf < 4; ++mf) sacc[rf][mf] = (float4v){0.f, 0.f, 0.f, 0.f};
    __builtin_amdgcn_s_setprio(1);
#pragma unroll
    for (int ks = 0; ks < NC32; ++ks)
#pragma unroll
      for (int mf = 0; mf < 4; ++mf) {
        short8v kf = *(const short8v*)(Ks + ((4 * ks + lg) * 64 + 16 * mf + lr) * 8);
#pragma unroll
        for (int rf = 0; rf < RF; ++rf)
          sacc[rf][mf] =
              __builtin_amdgcn_mfma_f32_16x16x32_bf16(qf[rf][ks], kf, sacc[rf][mf], 0, 0, 0);
      }
    __builtin_amdgcn_s_setprio(0);
    __syncthreads();

    float scal[RF][4];
#pragma unroll
    for (int rf = 0; rf < RF; ++rf)
#pragma unroll
      for (int r = 0; r < 4; ++r) {
        float pm = fmaxf(fmaxf(sacc[rf][0][r], sacc[rf][1][r]),
                         fmaxf(sacc[rf][2][r], sacc[rf][3][r]));
#pragma unroll
        for (int off = 1; off < 16; off <<= 1) pm = fmaxf(pm, __shfl_xor(pm, off));
        float mnew = fmaxf(mrun[rf][r], pm);
        float sc = __expf(mrun[rf][r] - mnew);
        mrun[rf][r] = mnew;
        float rs = 0.f;
#pragma unroll
        for (int mf = 0; mf < 4; ++mf) {
          float p = __expf(sacc[rf][mf][r] - mnew);
          rs += p;
          Ps[(size_t)(w * QB + 16 * rf + 4 * lg + r) * 72 + 16 * mf + lr] =
              __float2bfloat16(p);
        }
#pragma unroll
        for (int off = 1; off < 16; off <<= 1) rs += __shfl_xor(rs, off);
        lrun[rf][r] = lrun[rf][r] * sc + rs;
        scal[rf][r] = sc;
      }
#pragma unroll
    for (int rf = 0; rf < RF; ++rf)
#pragma unroll
      for (int f = 0; f < NCF; ++f)
#pragma unroll
        for (int r = 0; r < 4; ++r) oacc[rf][f][r] *= scal[rf][r];

    asm volatile("s_waitcnt lgkmcnt(0)" ::: "memory");

    short8v pa[RF][2];
#pragma unroll
    for (int rf = 0; rf < RF; ++rf)
#pragma unroll
      for (int h = 0; h < 2; ++h)
        pa[rf][h] = *(const short8v*)(Ps + (size_t)(w * QB + 16 * rf + lr) * 72 +
                                      32 * h + 8 * lg);
    __builtin_amdgcn_s_setprio(1);
#pragma unroll
    for (int cf = 0; cf < NCF; ++cf)
#pragma unroll
      for (int h = 0; h < 2; ++h) {
        short8v vf = *(const short8v*)(Vs + ((h * 4 + lg) * C + 16 * cf + lr) * 8);
#pragma unroll
        for (int rf = 0; rf < RF; ++rf)
          oacc[rf][cf] =
              __builtin_amdgcn_mfma_f32_16x16x32_bf16(pa[rf][h], vf, oacc[rf][cf], 0, 0, 0);
      }
    __builtin_amdgcn_s_setprio(0);
  }

  const size_t rbase = (size_t)(split * NB + b) * N;
#pragma unroll
  for (int rf = 0; rf < RF; ++rf)
#pragma unroll
    for (int r = 0; r < 4; ++r) {
      int n = n0 + QB * w + 16 * rf + 4 * lg + r;
      if (lr == 0) {
        ml[(rbase + n) * 2]     = mrun[rf][r];
        ml[(rbase + n) * 2 + 1] = lrun[rf][r];
      }
#pragma unroll
      for (int cf = 0; cf < NCF; ++cf)
        Opart[(rbase + n) * C + 16 * cf + lr] = __float2bfloat16(oacc[rf][cf][r]);
    }
}

// ---------------- flash7 (self): C-split across wave pairs + RF=2, shared P.
// Q: [B][N][C].  K: [B][C/8][N][8].  V: [B][N/8][C][8].  KV-split S=2.
// Waves: qhalf = w&1 (q-rows 32*qhalf..+32), chalf = w>>1 (channels 144*chalf..).
// Waves 0,1 (chalf=0) write shared P; defer-max THR=8.
template<int C>
__global__ __launch_bounds__(256, 2) void flash7_kernel(
    const __hip_bfloat16* __restrict__ Q, const __hip_bfloat16* __restrict__ K,
    const __hip_bfloat16* __restrict__ V,
    __hip_bfloat16* __restrict__ Opart, float* __restrict__ ml)
{
  constexpr int N    = NPIX;
  constexpr int NC32 = C / 32;        // 9
  constexpr int NCF  = C / 32;        // 9 c-frags per wave (half of C/16)
  constexpr int CH   = C / 2;         // 144 channel offset per half
  constexpr int KBYTES = 128 * C;     // 36864
  constexpr int NT   = (N / 2) / 64;  // 32

  __shared__ __align__(1024) char smem[256 * C];
  __hip_bfloat16* Ks = (__hip_bfloat16*)smem;              // [C/8][64][8]
  __hip_bfloat16* Vs = (__hip_bfloat16*)(smem + KBYTES);   // [8][C][8]
  __hip_bfloat16* Ps = (__hip_bfloat16*)smem;              // alias: [64][72]

  const int n0 = blockIdx.x * 64;
  const int split = blockIdx.y, b = blockIdx.z;
  const int tid = threadIdx.x, w = tid >> 6, lane = tid & 63;
  const int lg = lane >> 4, lr = lane & 15;
  const int qhalf = w & 1, chalf = w >> 1;

  const __hip_bfloat16* Kb = K + (size_t)b * N * C;
  const __hip_bfloat16* Vb = V + (size_t)b * N * C;

  // Q fragments: rows n0 + 32*qhalf + 16*rf + lr  (waves 0,2 duplicate; 1,3 dup)
  short8v qf[2][NC32];
#pragma unroll
  for (int rf = 0; rf < 2; ++rf) {
    const __hip_bfloat16* qp =
        Q + ((size_t)b * N + n0 + 32 * qhalf + 16 * rf + lr) * C + 8 * lg;
#pragma unroll
    for (int ks = 0; ks < NC32; ++ks) qf[rf][ks] = *(const short8v*)(qp + 32 * ks);
  }

  float4v oacc[2][NCF];               // 72 regs
#pragma unroll
  for (int rf = 0; rf < 2; ++rf)
#pragma unroll
    for (int f = 0; f < NCF; ++f) oacc[rf][f] = (float4v){0.f, 0.f, 0.f, 0.f};
  float mrun[2][4], lrun[2][4];
#pragma unroll
  for (int rf = 0; rf < 2; ++rf)
#pragma unroll
    for (int r = 0; r < 4; ++r) { mrun[rf][r] = -INFINITY; lrun[rf][r] = 0.f; }

  const int m0base = split * (N / 2);

  for (int t = 0; t < NT; ++t) {
    const int m0 = m0base + t * 64;
    __syncthreads();                  // (A) prev PV reads done (P,V,K free)
    // stage K (wave-uniform LDS dest, per-lane global src)
    for (int u = w; u < C / 8; u += 4)
      glld16(Kb + ((size_t)u * N + m0 + lane) * 8, Ks + u * 512);
    // stage V
    for (int u = w; u < C / 8; u += 4) {
      int s = u * 64 + lane;
      int kv8 = s / C, c = s % C;
      glld16(Vb + ((size_t)(m0 / 8 + kv8) * C + c) * 8, Vs + u * 512);
    }
    asm volatile("s_waitcnt vmcnt(0)" ::: "memory");
    __syncthreads();                  // (B) staged data visible

    // ---- S = Q^T K: 32 rows (RF=2) x 64 m per wave (dup across c-halves)
    float4v sacc[2][4];
#pragma unroll
    for (int rf = 0; rf < 2; ++rf)
#pragma unroll
      for (int mf = 0; mf < 4; ++mf) sacc[rf][mf] = (float4v){0.f, 0.f, 0.f, 0.f};
    __builtin_amdgcn_s_setprio(1);
#pragma unroll
    for (int ks = 0; ks < NC32; ++ks)
#pragma unroll
      for (int mf = 0; mf < 4; ++mf) {
        short8v kf = *(const short8v*)(Ks + ((4 * ks + lg) * 64 + 16 * mf + lr) * 8);
#pragma unroll
        for (int rf = 0; rf < 2; ++rf)
          sacc[rf][mf] =
              __builtin_amdgcn_mfma_f32_16x16x32_bf16(qf[rf][ks], kf, sacc[rf][mf], 0, 0, 0);
      }
    __builtin_amdgcn_s_setprio(0);
    __syncthreads();                  // (C) K reads done -> P region (alias) free

    // ---- online softmax with defer-max (THR=8); chalf==0 waves write shared P
    float pm[2][4];
#pragma unroll
    for (int rf = 0; rf < 2; ++rf)
#pragma unroll
      for (int r = 0; r < 4; ++r) {
        float p = fmaxf(fmaxf(sacc[rf][0][r], sacc[rf][1][r]),
                        fmaxf(sacc[rf][2][r], sacc[rf][3][r]));
#pragma unroll
        for (int off = 1; off < 16; off <<= 1) p = fmaxf(p, __shfl_xor(p, off));
        pm[rf][r] = p;
      }
    int myok = 1;
#pragma unroll
    for (int rf = 0; rf < 2; ++rf)
#pragma unroll
      for (int r = 0; r < 4; ++r)
        myok &= (pm[rf][r] <= mrun[rf][r] + 8.f) ? 1 : 0;
    if (__all(myok)) {
#pragma unroll
      for (int rf = 0; rf < 2; ++rf)
#pragma unroll
        for (int r = 0; r < 4; ++r) {
          float rs = 0.f;
#pragma unroll
          for (int mf = 0; mf < 4; ++mf) {
            float p = __expf(sacc[rf][mf][r] - mrun[rf][r]);
            rs += p;
            if (chalf == 0)
              Ps[(32 * qhalf + 16 * rf + 4 * lg + r) * 72 + 16 * mf + lr] =
                  __float2bfloat16(p);
          }
#pragma unroll
          for (int off = 1; off < 16; off <<= 1) rs += __shfl_xor(rs, off);
          lrun[rf][r] += rs;
        }
    } else {
      float scal[2][4];
#pragma unroll
      for (int rf = 0; rf < 2; ++rf)
#pragma unroll
        for (int r = 0; r < 4; ++r) {
          float mnew = fmaxf(mrun[rf][r], pm[rf][r]);
          float sc = __expf(mrun[rf][r] - mnew);
          mrun[rf][r] = mnew;
          float rs = 0.f;
#pragma unroll
          for (int mf = 0; mf < 4; ++mf) {
            float p = __expf(sacc[rf][mf][r] - mnew);
            rs += p;
            if (chalf == 0)
              Ps[(32 * qhalf + 16 * rf + 4 * lg + r) * 72 + 16 * mf + lr] =
                  __float2bfloat16(p);
          }
#pragma unroll
          for (int off = 1; off < 16; off <<= 1) rs += __shfl_xor(rs, off);
          lrun[rf][r] = lrun[rf][r] * sc + rs;
          scal[rf][r] = sc;
        }
#pragma unroll
      for (int rf = 0; rf < 2; ++rf)
#pragma unroll
        for (int f = 0; f < NCF; ++f)
#pragma unroll
          for (int r = 0; r < 4; ++r) oacc[rf][f][r] *= scal[rf][r];
    }

    __syncthreads();                  // (D) P visible to all waves

    // ---- O += P V^T (each wave: 32 rows x its 144 channels)
    short8v pa[2][2];
#pragma unroll
    for (int rf = 0; rf < 2; ++rf)
#pragma unroll
      for (int h = 0; h < 2; ++h)
        pa[rf][h] = *(const short8v*)(Ps + (32 * qhalf + 16 * rf + lr) * 72 +
                                      32 * h + 8 * lg);
    __builtin_amdgcn_s_setprio(1);
#pragma unroll
    for (int cf = 0; cf < NCF; ++cf) {
      int c = CH * chalf + 16 * cf + lr;
#pragma unroll
      for (int h = 0; h < 2; ++h) {
        short8v vf = *(const short8v*)(Vs + ((h * 4 + lg) * C + c) * 8);
#pragma unroll
        for (int rf = 0; rf < 2; ++rf)
          oacc[rf][cf] =
              __builtin_amdgcn_mfma_f32_16x16x32_bf16(pa[rf][h], vf, oacc[rf][cf], 0, 0, 0);
      }
    }
    __builtin_amdgcn_s_setprio(0);
  }

  // ---- epilogue: unnormalized partials (each wave its channel half)
  const size_t rbase = (size_t)(split * NB + b) * N;
#pragma unroll
  for (int rf = 0; rf < 2; ++rf)
#pragma unroll
    for (int r = 0; r < 4; ++r) {
      int n = n0 + 32 * qhalf + 16 * rf + 4 * lg + r;
      if (chalf == 0 && lr == 0) {
        ml[(rbase + n) * 2]     = mrun[rf][r];
        ml[(rbase + n) * 2 + 1] = lrun[rf][r];
      }
#pragma unroll
      for (int cf = 0; cf < NCF; ++cf)
        Opart[(rbase + n) * C + CH * chalf + 16 * cf + lr] =
            __float2bfloat16(oacc[rf][cf][r]);
    }
}

// ---------------- merge S splits + gamma + residual -> t bf16 [B][N][C]
template<int C, int S>
__global__ __launch_bounds__(256) void merge4_kernel(
    const __hip_bfloat16* __restrict__ Op, const float* __restrict__ ml,
    const float* __restrict__ R, const float* __restrict__ gamma_p,
    __hip_bfloat16* __restrict__ T)
{
  const size_t row = blockIdx.x;
  float m = -INFINITY;
#pragma unroll
  for (int s = 0; s < S; ++s)
    m = fmaxf(m, ml[((size_t)s * NB * NPIX + row) * 2]);
  float e[S]; float L = 0.f;
#pragma unroll
  for (int s = 0; s < S; ++s) {
    e[s] = __expf(ml[((size_t)s * NB * NPIX + row) * 2] - m);
    L += ml[((size_t)s * NB * NPIX + row) * 2 + 1] * e[s];
  }
  float rinv = gamma_p[0] / L;
  for (int c = threadIdx.x; c < C; c += 256) {
    float o = 0.f;
#pragma unroll
    for (int s = 0; s < S; ++s)
      o += __bfloat162float(Op[((size_t)s * NB * NPIX + row) * C + c]) * e[s];
    T[row * C + c] = __float2bfloat16(o * rinv + R[row * C + c]);
  }
}

// ---------------- conv5 (unchanged, known-good)
template<int IC>
__global__ __launch_bounds__(256, 1) void conv5_kernel(
    const __hip_bfloat16* __restrict__ X, const __hip_bfloat16* __restrict__ W2,
    float* __restrict__ Y)
{
  constexpr int NCH = IC / 32;
  constexpr int XP = 66 * 32;
  const int h0 = blockIdx.x * 4, o0 = blockIdx.y * 64, b = blockIdx.z;
  const int tid = threadIdx.x, wv = tid >> 6, lane = tid & 63;
  const int lg = lane >> 4, lr = lane & 15;

  __shared__ __align__(1024) __hip_bfloat16 Xs[2][6 * XP];
  __shared__ __align__(1024) __hip_bfloat16 Wsh[2][9 * 2048];

  const __hip_bfloat16 zz = __float2bfloat16(0.f);
  for (int e = tid; e < 384; e += 256) {
    int p = e / 64, side = (e >> 5) & 1, ch = e & 31;
    int sl = side ? 65 : 0;
    Xs[0][p * XP + sl * 32 + ch] = zz;
    Xs[1][p * XP + sl * 32 + ch] = zz;
  }
#pragma unroll
  for (int p = 0; p < 6; ++p) {
    int hs = h0 - 1 + p;
    if (hs < 0 || hs > 63) {
      for (int e = tid; e < XP; e += 256) {
        Xs[0][p * XP + e] = zz;
        Xs[1][p * XP + e] = zz;
      }
    }
  }
  __syncthreads();

  float4v acc[4][4];
#pragma unroll
  for (int pf = 0; pf < 4; ++pf)
#pragma unroll
    for (int of = 0; of < 4; ++of) acc[pf][of] = (float4v){0.f, 0.f, 0.f, 0.f};

#define CSTAGE(BUF, CI)                                                        \
  _Pragma("unroll")                                                            \
  for (int k = 0; k < 6; ++k) {                                                \
    int j = wv + k * 4;                                                        \
    int p = j >> 2, seg = j & 3;                                               \
    int hs = h0 - 1 + p;                                                       \
    if (hs >= 0 && hs < 64) {                                                  \
      int px = seg * 16 + (lane >> 2), ig = lane & 3;                          \
      int sl = px + 1;                                                         \
      glld16(X + ((size_t)(b * NPIX + hs * 64 + px)) * IC + (CI) * 32 +        \
                 8 * (ig ^ (sl & 3)),                                          \
             &Xs[BUF][p * XP + (1 + seg * 16) * 32]);                          \
    }                                                                          \
  }                                                                            \
  _Pragma("unroll")                                                            \
  for (int k = 0; k < 9; ++k) {                                                \
    int j = wv + k * 4;                                                        \
    int dydx = j >> 2, seg = j & 3;                                            \
    int oo = seg * 16 + (lane >> 2), ig = lane & 3;                            \
    glld16(W2 + ((size_t)(dydx * 256 + o0 + oo)) * IC + (CI) * 32 +            \
               8 * (ig ^ (oo & 3)),                                            \
           &Wsh[BUF][dydx * 2048 + seg * 512]);                                \
  }

  CSTAGE(0, 0);
  int cur = 0;
  for (int ci = 0; ci < NCH; ++ci) {
    asm volatile("s_waitcnt vmcnt(0) lgkmcnt(0)" ::: "memory");
    vbar();
    __builtin_amdgcn_sched_barrier(0);
    const int cn = (ci + 1 == NCH) ? 0 : ci + 1;
    if (cur) { CSTAGE(0, cn); } else { CSTAGE(1, cn); }
    const __hip_bfloat16* xb = &Xs[cur][0];
    const __hip_bfloat16* wb = &Wsh[cur][0];
    __builtin_amdgcn_s_setprio(1);
#pragma unroll
    for (int dy = 0; dy < 3; ++dy) {
      const __hip_bfloat16* xpl = xb + (wv + dy) * XP;
#pragma unroll
      for (int dx = 0; dx < 3; ++dx) {
        short8v a[4];
#pragma unroll
        for (int pf = 0; pf < 4; ++pf) {
          int sl = pf * 16 + lr + dx;
          a[pf] = *(const short8v*)(xpl + sl * 32 + 8 * (lg ^ (sl & 3)));
        }
#pragma unroll
        for (int of = 0; of < 4; ++of) {
          int br = 16 * of + lr;
          short8v bbv = *(const short8v*)(wb + (dy * 3 + dx) * 2048 + br * 32 +
                                          8 * (lg ^ (br & 3)));
#pragma unroll
          for (int pf = 0; pf < 4; ++pf)
            acc[pf][of] = __builtin_amdgcn_mfma_f32_16x16x32_bf16(a[pf], bbv,
                                                                  acc[pf][of], 0, 0, 0);
        }
      }
    }
    __builtin_amdgcn_s_setprio(0);
    cur ^= 1;
  }
#undef CSTAGE

#pragma unroll
  for (int pf = 0; pf < 4; ++pf)
#pragma unroll
    for (int r = 0; r < 4; ++r) {
      size_t row = (size_t)b * NPIX + (h0 + wv) * 64 + 16 * pf + 4 * lg + r;
#pragma unroll
      for (int of = 0; of < 4; ++of)
        Y[row * 256 + o0 + 16 * of + lr] = acc[pf][of][r];
    }
}

// ---------------- BN stats, two-stage. X: [16384][256] f32.
__global__ __launch_bounds__(256) void stats1_kernel(
    const float* __restrict__ X, float* __restrict__ Part)
{
  const int o0 = (blockIdx.x & 3) * 64;
  const int rc = blockIdx.x >> 2;
  const int tid = threadIdx.x;
  const int o = o0 + (tid & 63), rq = tid >> 6;
  float s = 0.f, sq = 0.f;
  for (int rr = rq; rr < 256; rr += 4) {
    float v = X[(size_t)(rc * 256 + rr) * 256 + o];
    s += v; sq += v * v;
  }
  __shared__ float rs[256], rq2[256];
  rs[tid] = s; rq2[tid] = sq;
  __syncthreads();
  if (tid < 64) {
    s  = rs[tid] + rs[tid + 64] + rs[tid + 128] + rs[tid + 192];
    sq = rq2[tid] + rq2[tid + 64] + rq2[tid + 128] + rq2[tid + 192];
    Part[(o0 + tid) * 128 + rc * 2]     = s;
    Part[(o0 + tid) * 128 + rc * 2 + 1] = sq;
  }
}

__global__ __launch_bounds__(256) void stats2_kernel(
    const float* __restrict__ Part, float* __restrict__ Mean, float* __restrict__ Rstd)
{
  const int o = threadIdx.x;
  float s = 0.f, sq = 0.f;
  for (int rc = 0; rc < 64; ++rc) {
    s += Part[o * 128 + rc * 2];
    sq += Part[o * 128 + rc * 2 + 1];
  }
  float mean = s / 16384.f;
  float var = sq / 16384.f - mean * mean;
  Mean[o] = mean;
  Rstd[o] = 1.f / sqrtf(var + 1e-5f);
}

// ---------------- BN apply #1 + ReLU + cat flow -> cat f32/bf16 [16384][288]
__global__ __launch_bounds__(320) void bnapply1_kernel(
    const float* __restrict__ X, const float* __restrict__ Flow,
    const float* __restrict__ Mean, const float* __restrict__ Rstd,
    const float* __restrict__ G, const float* __restrict__ Bt,
    float* __restrict__ CatF, __hip_bfloat16* __restrict__ CatB)
{
  const size_t row = blockIdx.x;
  const int t = threadIdx.x;
  if (t >= 288) return;
  float val;
  if (t < 256) {
    float v = X[row * 256 + t];
    val = fmaxf((v - Mean[t]) * Rstd[t] * G[t] + Bt[t], 0.f);
  } else if (t < 258) {
    int b = (int)(row >> 12), n = (int)(row & 4095);
    val = Flow[((size_t)(b * 2 + (t - 256)) << 12) + n];
  } else val = 0.f;
  CatF[row * 288 + t] = val;
  CatB[row * 288 + t] = __float2bfloat16(val);
}

// ---------------- BN apply #2 + ReLU, in place on [16384][256] f32
__global__ __launch_bounds__(256) void bnapply2_kernel(
    float* X, const float* __restrict__ Mean, const float* __restrict__ Rstd,
    const float* __restrict__ G, const float* __restrict__ Bt)
{
  const size_t idx = (size_t)blockIdx.x * 256 + threadIdx.x;
  const int t = threadIdx.x;
  float v = X[idx];
  X[idx] = fmaxf((v - Mean[t]) * Rstd[t] * G[t] + Bt[t], 0.f);
}

// ---------------- pred: out[row] = dot(X[row][0:256], W) + bias
__global__ __launch_bounds__(256) void pred3_kernel(
    const float* __restrict__ X, const float* __restrict__ Wp,
    const float* __restrict__ Bp, float* __restrict__ Out)
{
  const int wv = threadIdx.x >> 6, lane = threadIdx.x & 63;
  const size_t row = (size_t)blockIdx.x * 4 + wv;
  const float* xr = X + row * 256;
  float acc = 0.f;
#pragma unroll
  for (int cc = 0; cc < 4; ++cc) acc = fmaf(xr[cc * 64 + lane], Wp[cc * 64 + lane], acc);
#pragma unroll
  for (int off = 1; off < 64; off <<= 1) acc += __shfl_xor(acc, off);
  if (lane == 0) Out[row] = acc + Bp[0];
}

// ============================================================================
extern "C" void kernel_launch(void* const* d_in, const int* in_sizes, int n_in,
                              void* d_out, int out_size, void* d_ws, size_t ws_size,
                              hipStream_t stream)
{
  (void)in_sizes; (void)n_in; (void)out_size; (void)ws_size;
  const float* x      = (const float*)d_in[0];
  const float* y      = (const float*)d_in[1];
  const float* flow   = (const float*)d_in[2];
  const float* w1x1   = (const float*)d_in[3];
  const float* b1x1   = (const float*)d_in[4];
  const float* ca_wq  = (const float*)d_in[5];
  const float* ca_wk  = (const float*)d_in[6];
  const float* ca_wv  = (const float*)d_in[7];
  const float* ca_g   = (const float*)d_in[8];
  const float* cbr1_w = (const float*)d_in[9];
  const float* bn1_g  = (const float*)d_in[10];
  const float* bn1_b  = (const float*)d_in[11];
  const float* sa_wq  = (const float*)d_in[12];
  const float* sa_wk  = (const float*)d_in[13];
  const float* sa_wv  = (const float*)d_in[14];
  const float* sa_g   = (const float*)d_in[15];
  const float* cbr2_w = (const float*)d_in[16];
  const float* bn2_g  = (const float*)d_in[17];
  const float* bn2_b  = (const float*)d_in[18];
  const float* pred_w = (const float*)d_in[19];
  const float* pred_b = (const float*)d_in[20];
  float* out = (float*)d_out;

  // ---- workspace layout (float units)
  const size_t FSZ = (size_t)NB * NPIX * 288;       // 4,718,592 floats
  const size_t SSZ = FSZ / 2;                       // bf16 slot
  float* ws = (float*)d_ws;
  float* F0 = ws;                 // xT -> Opart -> conv outs
  float* F1 = ws + FSZ;           // yT -> cross Opart tail
  float* F2 = ws + 2 * FSZ;       // xb f32 (cross residual) -> cat f32 (self residual)
  float* Sb = ws + 3 * FSZ;
  __hip_bfloat16* S0 = (__hip_bfloat16*)(Sb);            // xb_bf -> t -> q2
  __hip_bfloat16* S1 = (__hip_bfloat16*)(Sb + SSZ);      // yb_bf -> k2
  __hip_bfloat16* S2 = (__hip_bfloat16*)(Sb + 2 * SSZ);  // q -> v2
  __hip_bfloat16* S3 = (__hip_bfloat16*)(Sb + 3 * SSZ);  // k -> catT
  __hip_bfloat16* S4 = (__hip_bfloat16*)(Sb + 4 * SSZ);  // v -> t2
  float* Wr = Sb + 5 * SSZ;
  __hip_bfloat16* w1bf  = (__hip_bfloat16*)Wr;                       // 256x512
  __hip_bfloat16* caqb  = w1bf + (size_t)256 * 512;                  // 256x256
  __hip_bfloat16* cakb  = caqb + (size_t)256 * 256;
  __hip_bfloat16* cavb  = cakb + (size_t)256 * 256;
  __hip_bfloat16* saqb  = cavb + (size_t)256 * 256;                  // 320x288
  __hip_bfloat16* sakb  = saqb + (size_t)320 * 288;
  __hip_bfloat16* savb  = sakb + (size_t)320 * 288;
  __hip_bfloat16* w2abf = savb + (size_t)320 * 288;                  // 9x256x256
  __hip_bfloat16* w2bbf = w2abf + (size_t)9 * 256 * 256;             // 9x256x288
  float* Part = (float*)(w2bbf + (size_t)9 * 256 * 288);             // 32768
  float* Mean = Part + 32768;                                        // 256
  float* Rstd = Mean + 256;                                          // 256
  float* Mlb  = Rstd + 256;                                          // 131072

  __hip_bfloat16* xT = (__hip_bfloat16*)F0;
  __hip_bfloat16* yT = (__hip_bfloat16*)F1;
  __hip_bfloat16* Op = (__hip_bfloat16*)F0;   // flash partials

  dim3 blk(256);

  // ---- fused weight prep (1 dispatch)
  wprep_all<<<dim3(48, 9), blk, 0, stream>>>(
      w1x1, ca_wq, ca_wk, ca_wv, sa_wq, sa_wk, sa_wv, cbr1_w, cbr2_w,
      w1bf, caqb, cakb, cavb, saqb, sakb, savb, w2abf, w2bbf);

  // ---- fused transpose x+y (1 dispatch)
  transp_kernel<<<dim3(8, 64, 8), blk, 0, stream>>>(x, y, xT, yT);

  // ---- xb (f32 + bf16), yb (bf16)
  gemm3_kernel<0><<<dim3(64, 4, 4), blk, 0, stream>>>(xT, w1bf, b1x1, F2, S0, 512, 256);
  gemm3_kernel<1><<<dim3(64, 4, 4), blk, 0, stream>>>(yT, w1bf, b1x1, nullptr, S1, 512, 256);

  // ---- cross q [n][C], k chunk, v chunk
  gemm3_kernel<1><<<dim3(64, 4, 4), blk, 0, stream>>>(S0, caqb, nullptr, nullptr, S2, 256, 256);
  gemm3_kernel<3><<<dim3(64, 4, 4), blk, 0, stream>>>(S1, cakb, nullptr, nullptr, S3, 256, 256);
  gemm3_kernel<4><<<dim3(64, 4, 4), blk, 0, stream>>>(S1, cavb, nullptr, nullptr, S4, 256, 256);

  // ---- cross flash (QB=32, split 4) + merge: t = gamma*attn + xb -> S0
  flash4_kernel<256, 2, 4><<<dim3(32, 4, 4), blk, 0, stream>>>(S2, S3, S4, Op, Mlb);
  merge4_kernel<256, 4><<<dim3(16384), blk, 0, stream>>>(Op, Mlb, F2, ca_g, S0);

  // ---- conv1 + BN + ReLU + cat (cat f32 -> F2)
  conv5_kernel<256><<<dim3(16, 4, 4), blk, 0, stream>>>(S0, w2abf, F0);
  stats1_kernel<<<dim3(256), blk, 0, stream>>>(F0, Part);
  stats2_kernel<<<dim3(1), blk, 0, stream>>>(Part, Mean, Rstd);
  bnapply1_kernel<<<dim3(16384), dim3(320), 0, stream>>>(F0, flow, Mean, Rstd,
                                                         bn1_g, bn1_b, F2, S3);

  // ---- self q2 [n][288], k2 chunk, v2 chunk
  gemm3_kernel<1><<<dim3(64, 5, 4), blk, 0, stream>>>(S3, saqb, nullptr, nullptr, S0, 288, 288);
  gemm3_kernel<3><<<dim3(64, 5, 4), blk, 0, stream>>>(S3, sakb, nullptr, nullptr, S1, 288, 288);
  gemm3_kernel<4><<<dim3(64, 5, 4), blk, 0, stream>>>(S3, savb, nullptr, nullptr, S2, 288, 288);

  // ---- self flash7 (C-split, split 2) + merge: t2 -> S4 (R = cat f32 in F2)
  flash7_kernel<288><<<dim3(64, 2, 4), blk, 0, stream>>>(S0, S1, S2, Op, Mlb);
  merge4_kernel<288, 2><<<dim3(16384), blk, 0, stream>>>(Op, Mlb, F2, sa_g, S4);

  // ---- conv2 + BN + ReLU (in place), pred
  conv5_kernel<288><<<dim3(16, 4, 4), blk, 0, stream>>>(S4, w2bbf, F0);
  stats1_kernel<<<dim3(256), blk, 0, stream>>>(F0, Part);
  stats2_kernel<<<dim3(1), blk, 0, stream>>>(Part, Mean, Rstd);
  bnapply2_kernel<<<dim3(16384), blk, 0, stream>>>(F0, Mean, Rstd, bn2_g, bn2_b);

  pred3_kernel<<<dim3(4096), blk, 0, stream>>>(F0, pred_w, pred_b, out);
}

// Round 10
// 507.463 us; speedup vs baseline: 1.9448x; 1.5496x over previous
//
#include <hip/hip_runtime.h>
#include <hip/hip_bf16.h>
#include <math.h>

// ============================================================================
// Round 9: rollback self-attn to flash4<288,1,2> (validated local optimum:
// 147us, no spill). Keep round-7/8 infra (gemm3-dbuf, fused wprep/transp,
// conv5). New: fuse bnapply2+pred -> bnpred (saves 134MB traffic + 1 dispatch).
// Register-wall note: any flash variant with >72 acc regs + 36 Q regs spills
// (rounds 5/7/8 evidence). Do not retry without a layout that shrinks O-state.
// ============================================================================

#define NPIX 4096
#define NB   4

typedef __attribute__((ext_vector_type(8))) short short8v;
typedef __attribute__((ext_vector_type(4))) float float4v;

__device__ __forceinline__ short f2bs(float f) {
  __hip_bfloat16 h = __float2bfloat16(f);
  short r; __builtin_memcpy(&r, &h, 2); return r;
}

__device__ __forceinline__ void glld16(const void* g, void* l) {
  __builtin_amdgcn_global_load_lds(
      (const __attribute__((address_space(1))) unsigned int*)g,
      (__attribute__((address_space(3))) unsigned int*)l, 16, 0, 0);
}

__device__ __forceinline__ void vbar() { __builtin_amdgcn_s_barrier(); }

// ---------------- fused transpose: z<4 -> x, else y.  [B][512][N] f32 -> [B][N][512] bf16
__global__ __launch_bounds__(256) void transp_kernel(
    const float* __restrict__ X, const float* __restrict__ Y,
    __hip_bfloat16* __restrict__ XT, __hip_bfloat16* __restrict__ YT)
{
  const int i0 = blockIdx.x * 64, n0 = blockIdx.y * 64;
  const int z = blockIdx.z, b = z & 3;
  const float* S = (z < 4) ? X : Y;
  __hip_bfloat16* D = (z < 4) ? XT : YT;
  const int tid = threadIdx.x;
  __shared__ float Ls[64][68];
#pragma unroll
  for (int it = 0; it < 4; ++it) {
    int ir = it * 16 + (tid >> 4);
    int nc = (tid & 15) * 4;
    float4 v = *(const float4*)(S + ((size_t)b * 512 + i0 + ir) * NPIX + n0 + nc);
    *(float4*)(&Ls[ir][nc]) = v;
  }
  __syncthreads();
#pragma unroll
  for (int ot = 0; ot < 2; ++ot) {
    int n = ot * 32 + (tid >> 3);
    int ig = tid & 7;
    short8v o;
#pragma unroll
    for (int j = 0; j < 8; ++j) o[j] = f2bs(Ls[8 * ig + j][n]);
    *(short8v*)(D + ((size_t)b * NPIX + n0 + n) * 512 + i0 + 8 * ig) = o;
  }
}

// ---------------- fused weight prep (9 segments in one dispatch)
__global__ void wprep_all(
    const float* __restrict__ w1, const float* __restrict__ cq,
    const float* __restrict__ ck, const float* __restrict__ cv,
    const float* __restrict__ sq, const float* __restrict__ sk,
    const float* __restrict__ sv, const float* __restrict__ c1,
    const float* __restrict__ c2,
    __hip_bfloat16* __restrict__ w1o, __hip_bfloat16* __restrict__ cqo,
    __hip_bfloat16* __restrict__ cko, __hip_bfloat16* __restrict__ cvo,
    __hip_bfloat16* __restrict__ sqo, __hip_bfloat16* __restrict__ sko,
    __hip_bfloat16* __restrict__ svo, __hip_bfloat16* __restrict__ c1o,
    __hip_bfloat16* __restrict__ c2o)
{
  const int seg = blockIdx.y;
  const float* src; __hip_bfloat16* dst;
  int Or, Ir, Op, Ip, isconv = 0;
  switch (seg) {
    case 0: src = w1; dst = w1o; Or = 256; Ir = 512; Op = 256; Ip = 512; break;
    case 1: src = cq; dst = cqo; Or = 256; Ir = 256; Op = 256; Ip = 256; break;
    case 2: src = ck; dst = cko; Or = 256; Ir = 256; Op = 256; Ip = 256; break;
    case 3: src = cv; dst = cvo; Or = 256; Ir = 256; Op = 256; Ip = 256; break;
    case 4: src = sq; dst = sqo; Or = 258; Ir = 258; Op = 320; Ip = 288; break;
    case 5: src = sk; dst = sko; Or = 258; Ir = 258; Op = 320; Ip = 288; break;
    case 6: src = sv; dst = svo; Or = 258; Ir = 258; Op = 320; Ip = 288; break;
    case 7: src = c1; dst = c1o; Or = 256; Ir = 256; Op = 256; Ip = 256; isconv = 1; break;
    default: src = c2; dst = c2o; Or = 256; Ir = 258; Op = 256; Ip = 288; isconv = 1; break;
  }
  if (!isconv) {
    size_t total = (size_t)Op * Ip;
    for (size_t e = (size_t)blockIdx.x * 256 + threadIdx.x; e < total;
         e += (size_t)gridDim.x * 256) {
      int i = (int)(e % Ip), o = (int)(e / Ip);
      float v = (o < Or && i < Ir) ? src[(size_t)o * Ir + i] : 0.f;
      dst[e] = __float2bfloat16(v);
    }
  } else {
    size_t total = (size_t)9 * Op * Ip;
    for (size_t e = (size_t)blockIdx.x * 256 + threadIdx.x; e < total;
         e += (size_t)gridDim.x * 256) {
      int i = (int)(e % Ip);
      size_t r = e / Ip;
      int o = (int)(r % Op);
      int dydx = (int)(r / Op);
      float v = (i < Ir) ? src[((size_t)o * Ir + i) * 9 + dydx] : 0.f;
      dst[e] = __float2bfloat16(v);
    }
  }
}

// ---------------- MFMA 1x1 GEMM, glld16 + dbuf LDS (round-7 proven).
template<int OMODE>
__global__ __launch_bounds__(256, 3) void gemm3_kernel(
    const __hip_bfloat16* __restrict__ X, const __hip_bfloat16* __restrict__ Wb,
    const float* __restrict__ Bias, float* __restrict__ Yf,
    __hip_bfloat16* __restrict__ Yb, int Ip, int O)
{
  const int n0 = blockIdx.x * 64, o0 = blockIdx.y * 64, b = blockIdx.z;
  const int tid = threadIdx.x, wv = tid >> 6, lane = tid & 63;
  const int lg = lane >> 4, lr = lane & 15;
  __shared__ __align__(1024) __hip_bfloat16 Xs[2][64 * 32];
  __shared__ __align__(1024) __hip_bfloat16 Wsh[2][64 * 32];

  const int nn = tid >> 2, ig = tid & 3;
  const __hip_bfloat16* xsrc = X + ((size_t)b * NPIX + n0 + nn) * Ip + 8 * (ig ^ (nn & 3));
  const __hip_bfloat16* wsrc = Wb + (size_t)(o0 + nn) * Ip + 8 * (ig ^ (nn & 3));

  float4v acc[4];
#pragma unroll
  for (int f = 0; f < 4; ++f) acc[f] = (float4v){0.f, 0.f, 0.f, 0.f};

  const int nch = Ip >> 5;

#define GSTAGE(BUF, CI)                            \
  glld16(xsrc + (CI) * 32, &Xs[BUF][tid * 8]);     \
  glld16(wsrc + (CI) * 32, &Wsh[BUF][tid * 8]);

  GSTAGE(0, 0);
  int cur = 0;
  for (int ci = 0; ci < nch; ++ci) {
    asm volatile("s_waitcnt vmcnt(0)" ::: "memory");
    __syncthreads();
    if (ci + 1 < nch) {
      if (cur) { GSTAGE(0, ci + 1); } else { GSTAGE(1, ci + 1); }
    }
    const __hip_bfloat16* xb = &Xs[cur][0];
    const __hip_bfloat16* wb = &Wsh[cur][0];
    if (OMODE != 4) {
      int ar = 16 * wv + lr;
      short8v a = *(const short8v*)(xb + ar * 32 + 8 * (lg ^ (ar & 3)));
#pragma unroll
      for (int of = 0; of < 4; ++of) {
        int br = 16 * of + lr;
        short8v bbv = *(const short8v*)(wb + br * 32 + 8 * (lg ^ (br & 3)));
        acc[of] = __builtin_amdgcn_mfma_f32_16x16x32_bf16(a, bbv, acc[of], 0, 0, 0);
      }
    } else {
      int ar = 16 * wv + lr;
      short8v a = *(const short8v*)(wb + ar * 32 + 8 * (lg ^ (ar & 3)));
#pragma unroll
      for (int nf = 0; nf < 4; ++nf) {
        int br = 16 * nf + lr;
        short8v bbv = *(const short8v*)(xb + br * 32 + 8 * (lg ^ (br & 3)));
        acc[nf] = __builtin_amdgcn_mfma_f32_16x16x32_bf16(a, bbv, acc[nf], 0, 0, 0);
      }
    }
    cur ^= 1;
  }
#undef GSTAGE

  if (OMODE < 2) {
#pragma unroll
    for (int r = 0; r < 4; ++r) {
      size_t row = (size_t)b * NPIX + n0 + 16 * wv + 4 * lg + r;
#pragma unroll
      for (int of = 0; of < 4; ++of) {
        int o = o0 + 16 * of + lr;
        if (o < O) {
          float v = acc[of][r] + (Bias ? Bias[o] : 0.f);
          if (OMODE == 0) Yf[row * O + o] = v;
          Yb[row * O + o] = __float2bfloat16(v);
        }
      }
    }
  } else if (OMODE == 3) {
    __hip_bfloat16* Hb = Yb + (size_t)b * NPIX * O;
#pragma unroll
    for (int r = 0; r < 4; ++r) {
      size_t n = n0 + 16 * wv + 4 * lg + r;
#pragma unroll
      for (int of = 0; of < 4; ++of) {
        int o = o0 + 16 * of + lr;
        if (o < O)
          Hb[((size_t)(o >> 3) * NPIX + n) * 8 + (o & 7)] = __float2bfloat16(acc[of][r]);
      }
    }
  } else {  // OMODE 4
    __hip_bfloat16* Hb = Yb + (size_t)b * NPIX * O;
#pragma unroll
    for (int r = 0; r < 4; ++r) {
      int c = o0 + 16 * wv + 4 * lg + r;
      if (c < O) {
#pragma unroll
        for (int nf = 0; nf < 4; ++nf) {
          int n = n0 + 16 * nf + lr;
          Hb[((size_t)(n >> 3) * O + c) * 8 + (n & 7)] = __float2bfloat16(acc[nf][r]);
        }
      }
    }
  }
}

// ---------------- flash4 (known-good): chunked conflict-free LDS + glld16.
// Q: [B][N][C].  K: [B][C/8][N][8].  V: [B][N/8][C][8].
template<int C, int RF, int S>
__global__ __launch_bounds__(256, 2) void flash4_kernel(
    const __hip_bfloat16* __restrict__ Q, const __hip_bfloat16* __restrict__ K,
    const __hip_bfloat16* __restrict__ V,
    __hip_bfloat16* __restrict__ Opart, float* __restrict__ ml)
{
  constexpr int N    = NPIX;
  constexpr int NC32 = C / 32;
  constexpr int NCF  = C / 16;
  constexpr int QB   = 16 * RF;
  constexpr int KBYTES = 128 * C;
  constexpr int NT   = (N / S) / 64;

  __shared__ __align__(1024) char smem[256 * C];
  __hip_bfloat16* Ks = (__hip_bfloat16*)smem;
  __hip_bfloat16* Vs = (__hip_bfloat16*)(smem + KBYTES);
  __hip_bfloat16* Ps = (__hip_bfloat16*)smem;   // alias

  const int n0 = blockIdx.x * (4 * QB);
  const int split = blockIdx.y, b = blockIdx.z;
  const int tid = threadIdx.x, w = tid >> 6, lane = tid & 63;
  const int lg = lane >> 4, lr = lane & 15;

  const __hip_bfloat16* Kb = K + (size_t)b * N * C;
  const __hip_bfloat16* Vb = V + (size_t)b * N * C;

  short8v qf[RF][NC32];
#pragma unroll
  for (int rf = 0; rf < RF; ++rf) {
    const __hip_bfloat16* qp =
        Q + ((size_t)b * N + n0 + QB * w + 16 * rf + lr) * C + 8 * lg;
#pragma unroll
    for (int ks = 0; ks < NC32; ++ks) qf[rf][ks] = *(const short8v*)(qp + 32 * ks);
  }

  float4v oacc[RF][NCF];
#pragma unroll
  for (int rf = 0; rf < RF; ++rf)
#pragma unroll
    for (int f = 0; f < NCF; ++f) oacc[rf][f] = (float4v){0.f, 0.f, 0.f, 0.f};
  float mrun[RF][4], lrun[RF][4];
#pragma unroll
  for (int rf = 0; rf < RF; ++rf)
#pragma unroll
    for (int r = 0; r < 4; ++r) { mrun[rf][r] = -INFINITY; lrun[rf][r] = 0.f; }

  const int m0base = split * (N / S);

  for (int t = 0; t < NT; ++t) {
    const int m0 = m0base + t * 64;
    __syncthreads();
    for (int u = w; u < C / 8; u += 4)
      glld16(Kb + ((size_t)u * N + m0 + lane) * 8, Ks + u * 512);
    for (int u = w; u < C / 8; u += 4) {
      int s = u * 64 + lane;
      int kv8 = s / C, c = s % C;
      glld16(Vb + ((size_t)(m0 / 8 + kv8) * C + c) * 8, Vs + u * 512);
    }
    asm volatile("s_waitcnt vmcnt(0)" ::: "memory");
    __syncthreads();

    float4v sacc[RF][4];
#pragma unroll
    for (int rf = 0; rf < RF; ++rf)
#pragma unroll
      for (int mf = 0; mf < 4; ++mf) sacc[rf][mf] = (float4v){0.f, 0.f, 0.f, 0.f};
    __builtin_amdgcn_s_setprio(1);
#pragma unroll
    for (int ks = 0; ks < NC32; ++ks)
#pragma unroll
      for (int mf = 0; mf < 4; ++mf) {
        short8v kf = *(const short8v*)(Ks + ((4 * ks + lg) * 64 + 16 * mf + lr) * 8);
#pragma unroll
        for (int rf = 0; rf < RF; ++rf)
          sacc[rf][mf] =
              __builtin_amdgcn_mfma_f32_16x16x32_bf16(qf[rf][ks], kf, sacc[rf][mf], 0, 0, 0);
      }
    __builtin_amdgcn_s_setprio(0);
    __syncthreads();

    float scal[RF][4];
#pragma unroll
    for (int rf = 0; rf < RF; ++rf)
#pragma unroll
      for (int r = 0; r < 4; ++r) {
        float pm = fmaxf(fmaxf(sacc[rf][0][r], sacc[rf][1][r]),
                         fmaxf(sacc[rf][2][r], sacc[rf][3][r]));
#pragma unroll
        for (int off = 1; off < 16; off <<= 1) pm = fmaxf(pm, __shfl_xor(pm, off));
        float mnew = fmaxf(mrun[rf][r], pm);
        float sc = __expf(mrun[rf][r] - mnew);
        mrun[rf][r] = mnew;
        float rs = 0.f;
#pragma unroll
        for (int mf = 0; mf < 4; ++mf) {
          float p = __expf(sacc[rf][mf][r] - mnew);
          rs += p;
          Ps[(size_t)(w * QB + 16 * rf + 4 * lg + r) * 72 + 16 * mf + lr] =
              __float2bfloat16(p);
        }
#pragma unroll
        for (int off = 1; off < 16; off <<= 1) rs += __shfl_xor(rs, off);
        lrun[rf][r] = lrun[rf][r] * sc + rs;
        scal[rf][r] = sc;
      }
#pragma unroll
    for (int rf = 0; rf < RF; ++rf)
#pragma unroll
      for (int f = 0; f < NCF; ++f)
#pragma unroll
        for (int r = 0; r < 4; ++r) oacc[rf][f][r] *= scal[rf][r];

    asm volatile("s_waitcnt lgkmcnt(0)" ::: "memory");

    short8v pa[RF][2];
#pragma unroll
    for (int rf = 0; rf < RF; ++rf)
#pragma unroll
      for (int h = 0; h < 2; ++h)
        pa[rf][h] = *(const short8v*)(Ps + (size_t)(w * QB + 16 * rf + lr) * 72 +
                                      32 * h + 8 * lg);
    __builtin_amdgcn_s_setprio(1);
#pragma unroll
    for (int cf = 0; cf < NCF; ++cf)
#pragma unroll
      for (int h = 0; h < 2; ++h) {
        short8v vf = *(const short8v*)(Vs + ((h * 4 + lg) * C + 16 * cf + lr) * 8);
#pragma unroll
        for (int rf = 0; rf < RF; ++rf)
          oacc[rf][cf] =
              __builtin_amdgcn_mfma_f32_16x16x32_bf16(pa[rf][h], vf, oacc[rf][cf], 0, 0, 0);
      }
    __builtin_amdgcn_s_setprio(0);
  }

  const size_t rbase = (size_t)(split * NB + b) * N;
#pragma unroll
  for (int rf = 0; rf < RF; ++rf)
#pragma unroll
    for (int r = 0; r < 4; ++r) {
      int n = n0 + QB * w + 16 * rf + 4 * lg + r;
      if (lr == 0) {
        ml[(rbase + n) * 2]     = mrun[rf][r];
        ml[(rbase + n) * 2 + 1] = lrun[rf][r];
      }
#pragma unroll
      for (int cf = 0; cf < NCF; ++cf)
        Opart[(rbase + n) * C + 16 * cf + lr] = __float2bfloat16(oacc[rf][cf][r]);
    }
}

// ---------------- merge S splits + gamma + residual -> t bf16 [B][N][C]
template<int C, int S>
__global__ __launch_bounds__(256) void merge4_kernel(
    const __hip_bfloat16* __restrict__ Op, const float* __restrict__ ml,
    const float* __restrict__ R, const float* __restrict__ gamma_p,
    __hip_bfloat16* __restrict__ T)
{
  const size_t row = blockIdx.x;
  float m = -INFINITY;
#pragma unroll
  for (int s = 0; s < S; ++s)
    m = fmaxf(m, ml[((size_t)s * NB * NPIX + row) * 2]);
  float e[S]; float L = 0.f;
#pragma unroll
  for (int s = 0; s < S; ++s) {
    e[s] = __expf(ml[((size_t)s * NB * NPIX + row) * 2] - m);
    L += ml[((size_t)s * NB * NPIX + row) * 2 + 1] * e[s];
  }
  float rinv = gamma_p[0] / L;
  for (int c = threadIdx.x; c < C; c += 256) {
    float o = 0.f;
#pragma unroll
    for (int s = 0; s < S; ++s)
      o += __bfloat162float(Op[((size_t)s * NB * NPIX + row) * C + c]) * e[s];
    T[row * C + c] = __float2bfloat16(o * rinv + R[row * C + c]);
  }
}

// ---------------- conv5 (unchanged, known-good)
template<int IC>
__global__ __launch_bounds__(256, 1) void conv5_kernel(
    const __hip_bfloat16* __restrict__ X, const __hip_bfloat16* __restrict__ W2,
    float* __restrict__ Y)
{
  constexpr int NCH = IC / 32;
  constexpr int XP = 66 * 32;
  const int h0 = blockIdx.x * 4, o0 = blockIdx.y * 64, b = blockIdx.z;
  const int tid = threadIdx.x, wv = tid >> 6, lane = tid & 63;
  const int lg = lane >> 4, lr = lane & 15;

  __shared__ __align__(1024) __hip_bfloat16 Xs[2][6 * XP];
  __shared__ __align__(1024) __hip_bfloat16 Wsh[2][9 * 2048];

  const __hip_bfloat16 zz = __float2bfloat16(0.f);
  for (int e = tid; e < 384; e += 256) {
    int p = e / 64, side = (e >> 5) & 1, ch = e & 31;
    int sl = side ? 65 : 0;
    Xs[0][p * XP + sl * 32 + ch] = zz;
    Xs[1][p * XP + sl * 32 + ch] = zz;
  }
#pragma unroll
  for (int p = 0; p < 6; ++p) {
    int hs = h0 - 1 + p;
    if (hs < 0 || hs > 63) {
      for (int e = tid; e < XP; e += 256) {
        Xs[0][p * XP + e] = zz;
        Xs[1][p * XP + e] = zz;
      }
    }
  }
  __syncthreads();

  float4v acc[4][4];
#pragma unroll
  for (int pf = 0; pf < 4; ++pf)
#pragma unroll
    for (int of = 0; of < 4; ++of) acc[pf][of] = (float4v){0.f, 0.f, 0.f, 0.f};

#define CSTAGE(BUF, CI)                                                        \
  _Pragma("unroll")                                                            \
  for (int k = 0; k < 6; ++k) {                                                \
    int j = wv + k * 4;                                                        \
    int p = j >> 2, seg = j & 3;                                               \
    int hs = h0 - 1 + p;                                                       \
    if (hs >= 0 && hs < 64) {                                                  \
      int px = seg * 16 + (lane >> 2), ig = lane & 3;                          \
      int sl = px + 1;                                                         \
      glld16(X + ((size_t)(b * NPIX + hs * 64 + px)) * IC + (CI) * 32 +        \
                 8 * (ig ^ (sl & 3)),                                          \
             &Xs[BUF][p * XP + (1 + seg * 16) * 32]);                          \
    }                                                                          \
  }                                                                            \
  _Pragma("unroll")                                                            \
  for (int k = 0; k < 9; ++k) {                                                \
    int j = wv + k * 4;                                                        \
    int dydx = j >> 2, seg = j & 3;                                            \
    int oo = seg * 16 + (lane >> 2), ig = lane & 3;                            \
    glld16(W2 + ((size_t)(dydx * 256 + o0 + oo)) * IC + (CI) * 32 +            \
               8 * (ig ^ (oo & 3)),                                            \
           &Wsh[BUF][dydx * 2048 + seg * 512]);                                \
  }

  CSTAGE(0, 0);
  int cur = 0;
  for (int ci = 0; ci < NCH; ++ci) {
    asm volatile("s_waitcnt vmcnt(0) lgkmcnt(0)" ::: "memory");
    vbar();
    __builtin_amdgcn_sched_barrier(0);
    const int cn = (ci + 1 == NCH) ? 0 : ci + 1;
    if (cur) { CSTAGE(0, cn); } else { CSTAGE(1, cn); }
    const __hip_bfloat16* xb = &Xs[cur][0];
    const __hip_bfloat16* wb = &Wsh[cur][0];
    __builtin_amdgcn_s_setprio(1);
#pragma unroll
    for (int dy = 0; dy < 3; ++dy) {
      const __hip_bfloat16* xpl = xb + (wv + dy) * XP;
#pragma unroll
      for (int dx = 0; dx < 3; ++dx) {
        short8v a[4];
#pragma unroll
        for (int pf = 0; pf < 4; ++pf) {
          int sl = pf * 16 + lr + dx;
          a[pf] = *(const short8v*)(xpl + sl * 32 + 8 * (lg ^ (sl & 3)));
        }
#pragma unroll
        for (int of = 0; of < 4; ++of) {
          int br = 16 * of + lr;
          short8v bbv = *(const short8v*)(wb + (dy * 3 + dx) * 2048 + br * 32 +
                                          8 * (lg ^ (br & 3)));
#pragma unroll
          for (int pf = 0; pf < 4; ++pf)
            acc[pf][of] = __builtin_amdgcn_mfma_f32_16x16x32_bf16(a[pf], bbv,
                                                                  acc[pf][of], 0, 0, 0);
        }
      }
    }
    __builtin_amdgcn_s_setprio(0);
    cur ^= 1;
  }
#undef CSTAGE

#pragma unroll
  for (int pf = 0; pf < 4; ++pf)
#pragma unroll
    for (int r = 0; r < 4; ++r) {
      size_t row = (size_t)b * NPIX + (h0 + wv) * 64 + 16 * pf + 4 * lg + r;
#pragma unroll
      for (int of = 0; of < 4; ++of)
        Y[row * 256 + o0 + 16 * of + lr] = acc[pf][of][r];
    }
}

// ---------------- BN stats, two-stage. X: [16384][256] f32.
__global__ __launch_bounds__(256) void stats1_kernel(
    const float* __restrict__ X, float* __restrict__ Part)
{
  const int o0 = (blockIdx.x & 3) * 64;
  const int rc = blockIdx.x >> 2;
  const int tid = threadIdx.x;
  const int o = o0 + (tid & 63), rq = tid >> 6;
  float s = 0.f, sq = 0.f;
  for (int rr = rq; rr < 256; rr += 4) {
    float v = X[(size_t)(rc * 256 + rr) * 256 + o];
    s += v; sq += v * v;
  }
  __shared__ float rs[256], rq2[256];
  rs[tid] = s; rq2[tid] = sq;
  __syncthreads();
  if (tid < 64) {
    s  = rs[tid] + rs[tid + 64] + rs[tid + 128] + rs[tid + 192];
    sq = rq2[tid] + rq2[tid + 64] + rq2[tid + 128] + rq2[tid + 192];
    Part[(o0 + tid) * 128 + rc * 2]     = s;
    Part[(o0 + tid) * 128 + rc * 2 + 1] = sq;
  }
}

__global__ __launch_bounds__(256) void stats2_kernel(
    const float* __restrict__ Part, float* __restrict__ Mean, float* __restrict__ Rstd)
{
  const int o = threadIdx.x;
  float s = 0.f, sq = 0.f;
  for (int rc = 0; rc < 64; ++rc) {
    s += Part[o * 128 + rc * 2];
    sq += Part[o * 128 + rc * 2 + 1];
  }
  float mean = s / 16384.f;
  float var = sq / 16384.f - mean * mean;
  Mean[o] = mean;
  Rstd[o] = 1.f / sqrtf(var + 1e-5f);
}

// ---------------- BN apply #1 + ReLU + cat flow -> cat f32/bf16 [16384][288]
__global__ __launch_bounds__(320) void bnapply1_kernel(
    const float* __restrict__ X, const float* __restrict__ Flow,
    const float* __restrict__ Mean, const float* __restrict__ Rstd,
    const float* __restrict__ G, const float* __restrict__ Bt,
    float* __restrict__ CatF, __hip_bfloat16* __restrict__ CatB)
{
  const size_t row = blockIdx.x;
  const int t = threadIdx.x;
  if (t >= 288) return;
  float val;
  if (t < 256) {
    float v = X[row * 256 + t];
    val = fmaxf((v - Mean[t]) * Rstd[t] * G[t] + Bt[t], 0.f);
  } else if (t < 258) {
    int b = (int)(row >> 12), n = (int)(row & 4095);
    val = Flow[((size_t)(b * 2 + (t - 256)) << 12) + n];
  } else val = 0.f;
  CatF[row * 288 + t] = val;
  CatB[row * 288 + t] = __float2bfloat16(val);
}

// ---------------- fused BN apply #2 + ReLU + pred dot (saves 134MB traffic)
__global__ __launch_bounds__(256) void bnpred_kernel(
    const float* __restrict__ X, const float* __restrict__ Mean,
    const float* __restrict__ Rstd, const float* __restrict__ G,
    const float* __restrict__ Bt, const float* __restrict__ Wp,
    const float* __restrict__ Bp, float* __restrict__ Out)
{
  const int wv = threadIdx.x >> 6, lane = threadIdx.x & 63;
  const size_t row = (size_t)blockIdx.x * 4 + wv;
  const float* xr = X + row * 256;
  float acc = 0.f;
#pragma unroll
  for (int cc = 0; cc < 4; ++cc) {
    int c = cc * 64 + lane;
    float v = xr[c];
    v = fmaxf((v - Mean[c]) * Rstd[c] * G[c] + Bt[c], 0.f);
    acc = fmaf(v, Wp[c], acc);
  }
#pragma unroll
  for (int off = 1; off < 64; off <<= 1) acc += __shfl_xor(acc, off);
  if (lane == 0) Out[row] = acc + Bp[0];
}

// ============================================================================
extern "C" void kernel_launch(void* const* d_in, const int* in_sizes, int n_in,
                              void* d_out, int out_size, void* d_ws, size_t ws_size,
                              hipStream_t stream)
{
  (void)in_sizes; (void)n_in; (void)out_size; (void)ws_size;
  const float* x      = (const float*)d_in[0];
  const float* y      = (const float*)d_in[1];
  const float* flow   = (const float*)d_in[2];
  const float* w1x1   = (const float*)d_in[3];
  const float* b1x1   = (const float*)d_in[4];
  const float* ca_wq  = (const float*)d_in[5];
  const float* ca_wk  = (const float*)d_in[6];
  const float* ca_wv  = (const float*)d_in[7];
  const float* ca_g   = (const float*)d_in[8];
  const float* cbr1_w = (const float*)d_in[9];
  const float* bn1_g  = (const float*)d_in[10];
  const float* bn1_b  = (const float*)d_in[11];
  const float* sa_wq  = (const float*)d_in[12];
  const float* sa_wk  = (const float*)d_in[13];
  const float* sa_wv  = (const float*)d_in[14];
  const float* sa_g   = (const float*)d_in[15];
  const float* cbr2_w = (const float*)d_in[16];
  const float* bn2_g  = (const float*)d_in[17];
  const float* bn2_b  = (const float*)d_in[18];
  const float* pred_w = (const float*)d_in[19];
  const float* pred_b = (const float*)d_in[20];
  float* out = (float*)d_out;

  // ---- workspace layout (float units)
  const size_t FSZ = (size_t)NB * NPIX * 288;       // 4,718,592 floats
  const size_t SSZ = FSZ / 2;                       // bf16 slot
  float* ws = (float*)d_ws;
  float* F0 = ws;                 // xT -> Opart -> conv outs
  float* F1 = ws + FSZ;           // yT -> cross Opart tail
  float* F2 = ws + 2 * FSZ;       // xb f32 (cross residual) -> cat f32 (self residual)
  float* Sb = ws + 3 * FSZ;
  __hip_bfloat16* S0 = (__hip_bfloat16*)(Sb);            // xb_bf -> t -> q2
  __hip_bfloat16* S1 = (__hip_bfloat16*)(Sb + SSZ);      // yb_bf -> k2
  __hip_bfloat16* S2 = (__hip_bfloat16*)(Sb + 2 * SSZ);  // q -> v2
  __hip_bfloat16* S3 = (__hip_bfloat16*)(Sb + 3 * SSZ);  // k -> catT
  __hip_bfloat16* S4 = (__hip_bfloat16*)(Sb + 4 * SSZ);  // v -> t2
  float* Wr = Sb + 5 * SSZ;
  __hip_bfloat16* w1bf  = (__hip_bfloat16*)Wr;                       // 256x512
  __hip_bfloat16* caqb  = w1bf + (size_t)256 * 512;                  // 256x256
  __hip_bfloat16* cakb  = caqb + (size_t)256 * 256;
  __hip_bfloat16* cavb  = cakb + (size_t)256 * 256;
  __hip_bfloat16* saqb  = cavb + (size_t)256 * 256;                  // 320x288
  __hip_bfloat16* sakb  = saqb + (size_t)320 * 288;
  __hip_bfloat16* savb  = sakb + (size_t)320 * 288;
  __hip_bfloat16* w2abf = savb + (size_t)320 * 288;                  // 9x256x256
  __hip_bfloat16* w2bbf = w2abf + (size_t)9 * 256 * 256;             // 9x256x288
  float* Part = (float*)(w2bbf + (size_t)9 * 256 * 288);             // 32768
  float* Mean = Part + 32768;                                        // 256
  float* Rstd = Mean + 256;                                          // 256
  float* Mlb  = Rstd + 256;                                          // 131072

  __hip_bfloat16* xT = (__hip_bfloat16*)F0;
  __hip_bfloat16* yT = (__hip_bfloat16*)F1;
  __hip_bfloat16* Op = (__hip_bfloat16*)F0;   // flash partials

  dim3 blk(256);

  // ---- fused weight prep (1 dispatch)
  wprep_all<<<dim3(48, 9), blk, 0, stream>>>(
      w1x1, ca_wq, ca_wk, ca_wv, sa_wq, sa_wk, sa_wv, cbr1_w, cbr2_w,
      w1bf, caqb, cakb, cavb, saqb, sakb, savb, w2abf, w2bbf);

  // ---- fused transpose x+y (1 dispatch)
  transp_kernel<<<dim3(8, 64, 8), blk, 0, stream>>>(x, y, xT, yT);

  // ---- xb (f32 + bf16), yb (bf16)
  gemm3_kernel<0><<<dim3(64, 4, 4), blk, 0, stream>>>(xT, w1bf, b1x1, F2, S0, 512, 256);
  gemm3_kernel<1><<<dim3(64, 4, 4), blk, 0, stream>>>(yT, w1bf, b1x1, nullptr, S1, 512, 256);

  // ---- cross q [n][C], k chunk, v chunk
  gemm3_kernel<1><<<dim3(64, 4, 4), blk, 0, stream>>>(S0, caqb, nullptr, nullptr, S2, 256, 256);
  gemm3_kernel<3><<<dim3(64, 4, 4), blk, 0, stream>>>(S1, cakb, nullptr, nullptr, S3, 256, 256);
  gemm3_kernel<4><<<dim3(64, 4, 4), blk, 0, stream>>>(S1, cavb, nullptr, nullptr, S4, 256, 256);

  // ---- cross flash (QB=32, split 4) + merge: t = gamma*attn + xb -> S0
  flash4_kernel<256, 2, 4><<<dim3(32, 4, 4), blk, 0, stream>>>(S2, S3, S4, Op, Mlb);
  merge4_kernel<256, 4><<<dim3(16384), blk, 0, stream>>>(Op, Mlb, F2, ca_g, S0);

  // ---- conv1 + BN + ReLU + cat (cat f32 -> F2)
  conv5_kernel<256><<<dim3(16, 4, 4), blk, 0, stream>>>(S0, w2abf, F0);
  stats1_kernel<<<dim3(256), blk, 0, stream>>>(F0, Part);
  stats2_kernel<<<dim3(1), blk, 0, stream>>>(Part, Mean, Rstd);
  bnapply1_kernel<<<dim3(16384), dim3(320), 0, stream>>>(F0, flow, Mean, Rstd,
                                                         bn1_g, bn1_b, F2, S3);

  // ---- self q2 [n][288], k2 chunk, v2 chunk
  gemm3_kernel<1><<<dim3(64, 5, 4), blk, 0, stream>>>(S3, saqb, nullptr, nullptr, S0, 288, 288);
  gemm3_kernel<3><<<dim3(64, 5, 4), blk, 0, stream>>>(S3, sakb, nullptr, nullptr, S1, 288, 288);
  gemm3_kernel<4><<<dim3(64, 5, 4), blk, 0, stream>>>(S3, savb, nullptr, nullptr, S2, 288, 288);

  // ---- self flash4 (RF=1, split 2, validated) + merge: t2 -> S4 (R = cat in F2)
  flash4_kernel<288, 1, 2><<<dim3(64, 2, 4), blk, 0, stream>>>(S0, S1, S2, Op, Mlb);
  merge4_kernel<288, 2><<<dim3(16384), blk, 0, stream>>>(Op, Mlb, F2, sa_g, S4);

  // ---- conv2 + fused BN+ReLU+pred
  conv5_kernel<288><<<dim3(16, 4, 4), blk, 0, stream>>>(S4, w2bbf, F0);
  stats1_kernel<<<dim3(256), blk, 0, stream>>>(F0, Part);
  stats2_kernel<<<dim3(1), blk, 0, stream>>>(Part, Mean, Rstd);
  bnpred_kernel<<<dim3(4096), blk, 0, stream>>>(F0, Mean, Rstd, bn2_g, bn2_b,
                                                pred_w, pred_b, out);
}